// Round 1
// baseline (501.725 us; speedup 1.0000x reference)
//
#include <hip/hip_runtime.h>
#include <cstddef>

#define NB 2
#define RPB 4096
#define NRAY (NB*RPB)          // 8192
#define SC 48
#define SF 48
#define CP 32
#define HPX 256
#define HID 64
#define NOUT 33

#define DTC (1.05f/47.0f)
#define TC0 (2.25f + 0.5f*(1.05f/47.0f))

// d_out layout (floats)
#define OFF_DEPTH (NRAY*32)            // 262144
#define OFF_WSUM  (OFF_DEPTH + NRAY)   // 270336
#define OFF_SDF   (OFF_WSUM + NRAY)    // 278528

// ws layout (floats)
#define PT_OFF    0
#define PT_SIZE   ((size_t)NB*3*HPX*HPX*CP)          // 12,582,912
#define RGBC_OFF  (PT_SIZE)
#define RGBF_OFF  (RGBC_OFF + (size_t)NRAY*SC*32)
#define SIGF_OFF  (RGBF_OFF + (size_t)NRAY*SF*32)
#define TFINE_OFF (SIGF_OFF + (size_t)NRAY*SF)

static __device__ __forceinline__ float softplus_f(float x){
  return fmaxf(x, 0.0f) + log1pf(expf(-fabsf(x)));
}

// planes (b,pl,c,y,x) -> planesT (b,pl,y,x,c)
__global__ __launch_bounds__(256) void k_transpose(const float* __restrict__ src,
                                                   float* __restrict__ dst){
  int idx = blockIdx.x*256 + threadIdx.x;      // over NB*3*HPX*HPX = 393216
  int xy = idx & (HPX*HPX-1);
  int bp = idx >> 16;
  const float* s = src + (size_t)bp*CP*HPX*HPX + xy;
  float v[CP];
  #pragma unroll
  for (int c=0;c<CP;c++) v[c] = s[(size_t)c*HPX*HPX];
  float4* d4 = reinterpret_cast<float4*>(dst + (size_t)idx*CP);
  #pragma unroll
  for (int c=0;c<CP;c+=4) d4[c>>2] = make_float4(v[c],v[c+1],v[c+2],v[c+3]);
}

template<bool COARSE>
__global__ __launch_bounds__(256) void k_model(
    const float* __restrict__ pT,
    const float* __restrict__ orig,
    const float* __restrict__ dirs,
    const float* __restrict__ w1,
    const float* __restrict__ b1,
    const float* __restrict__ w2,
    const float* __restrict__ b2,
    const float* __restrict__ tfine,
    float* __restrict__ rgb_out,
    float* __restrict__ sig_out)
{
  int p = blockIdx.x*256 + threadIdx.x;        // point index, grid exact
  int ray = p / 48;
  int k = p - ray*48;
  int b = ray >> 12;                           // ray / 4096
  float t = COARSE ? (TC0 + (float)k*DTC) : tfine[p];
  float ox = orig[ray*3+0], oy = orig[ray*3+1], oz = orig[ray*3+2];
  float dx = dirs[ray*3+0], dy = dirs[ray*3+1], dz = dirs[ray*3+2];
  float cx = fmaf(t,dx,ox), cy = fmaf(t,dy,oy), cz = fmaf(t,dz,oz);

  float feat[CP];
  #pragma unroll
  for (int c=0;c<CP;c++) feat[c]=0.f;

  #pragma unroll
  for (int pl=0; pl<3; pl++){
    // plane 0: (x,y); plane 1: (x,z); plane 2: (z,x)
    float u = (pl==2)? cz : cx;
    float v = (pl==0)? cy : (pl==1 ? cz : cx);
    float x = ((u+1.0f)*256.0f - 1.0f)*0.5f;
    float y = ((v+1.0f)*256.0f - 1.0f)*0.5f;
    float xf = floorf(x), yf = floorf(y);
    float wx = x-xf, wy = y-yf;
    int ix = (int)xf, iy = (int)yf;
    const float* base = pT + ((size_t)(b*3+pl))*HPX*HPX*CP;
    float cw0 = (1.f-wx)*(1.f-wy), cw1 = wx*(1.f-wy), cw2 = (1.f-wx)*wy, cw3 = wx*wy;
    const int cxo[4] = {0,1,0,1};
    const int cyo[4] = {0,0,1,1};
    const float cww[4] = {cw0,cw1,cw2,cw3};
    #pragma unroll
    for (int corner=0; corner<4; corner++){
      int xi = ix + cxo[corner];
      int yi = iy + cyo[corner];
      if (xi>=0 && xi<HPX && yi>=0 && yi<HPX){
        const float4* q4 = reinterpret_cast<const float4*>(base + ((size_t)yi*HPX+xi)*CP);
        float wgt = cww[corner];
        #pragma unroll
        for (int q=0;q<8;q++){
          float4 f = q4[q];
          feat[q*4+0] = fmaf(wgt, f.x, feat[q*4+0]);
          feat[q*4+1] = fmaf(wgt, f.y, feat[q*4+1]);
          feat[q*4+2] = fmaf(wgt, f.z, feat[q*4+2]);
          feat[q*4+3] = fmaf(wgt, f.w, feat[q*4+3]);
        }
      }
    }
  }
  #pragma unroll
  for (int c=0;c<CP;c++) feat[c] *= (1.0f/3.0f);

  // MLP layer 1: 32 -> 64, softplus
  float h[HID];
  #pragma unroll
  for (int i=0;i<HID;i++){
    float a = b1[i];
    #pragma unroll
    for (int c=0;c<CP;c++) a = fmaf(feat[c], w1[c*HID+i], a);
    h[i] = softplus_f(a);
  }
  // layer 2 col 0 -> sigma
  {
    float a = b2[0];
    #pragma unroll
    for (int i=0;i<HID;i++) a = fmaf(h[i], w2[i*NOUT], a);
    sig_out[p] = a;
  }
  // layer 2 cols 1..32 -> rgb
  float* rp = rgb_out + (size_t)p*32;
  #pragma unroll 1
  for (int j=0;j<32;j+=4){
    float vv[4];
    #pragma unroll
    for (int q=0;q<4;q++){
      float a = b2[1+j+q];
      #pragma unroll
      for (int i=0;i<HID;i++) a = fmaf(h[i], w2[i*NOUT + 1+j+q], a);
      vv[q] = 1.0f/(1.0f+expf(-a))*1.002f - 0.001f;
    }
    *reinterpret_cast<float4*>(rp+j) = make_float4(vv[0],vv[1],vv[2],vv[3]);
  }
}

// coarse march -> weights -> importance CDF resample -> fine depths
__global__ __launch_bounds__(128) void k_importance(const float* __restrict__ sg_all,
                                                    float* __restrict__ tfine){
  __shared__ float sC[128][46];
  int tid = threadIdx.x;
  int ray = blockIdx.x*128 + tid;
  const float* sg = sg_all + (size_t)ray*SC;
  float T = 1.0f;
  float sum = 0.0f;
  float s_prev = sg[0];
  float wm1 = 0.f, wm2 = 0.f;
  for (int k=0;k<47;k++){
    float s_next = sg[k+1];
    float dm = softplus_f(0.5f*(s_prev+s_next)-1.0f);
    float alpha = 1.0f - expf(-dm*DTC);
    float wk = alpha*T;
    T *= (1.0f - alpha + 1e-10f);
    s_prev = s_next;
    if (k>=2){
      // q[m]=0.5*(max(w[m],w[m+1])+max(w[m+1],w[m+2]))+0.01, m=k-2 -> slot m+1
      float q = 0.5f*(fmaxf(wm2,wm1)+fmaxf(wm1,wk)) + 0.01f;
      sC[tid][k-1] = q;
      sum += q;
    }
    wm2 = wm1; wm1 = wk;
  }
  // build cdf in place: C[0]=0, C[i]=C[i-1]+q[i-1]/sum, i=1..45
  sC[tid][0] = 0.0f;
  float run = 0.0f;
  for (int i=1;i<=45;i++){
    run += sC[tid][i]/sum;
    sC[tid][i] = run;
  }
  float* tf = tfine + (size_t)ray*SF;
  int idx = 1;
  for (int j=0;j<48;j++){
    float u = (float)j/47.0f;
    while (idx<46 && sC[tid][idx] <= u) idx++;   // searchsorted right
    int below = idx-1;
    int above = (idx<46) ? idx : 45;
    float cb = sC[tid][below];
    float ca = sC[tid][above];
    float bb = TC0 + ((float)below+0.5f)*DTC;    // z_mid[below]
    float ba = TC0 + ((float)above+0.5f)*DTC;
    float denom = ca - cb;
    if (denom < 1e-5f) denom = 1.0f;
    tf[j] = bb + (u-cb)/denom*(ba-bb);
  }
}

// merge coarse+fine (stable, coarse first on tie) + final march; 32 lanes per ray
__global__ __launch_bounds__(256) void k_final(
    const float* __restrict__ sigc, const float* __restrict__ rgbc,
    const float* __restrict__ sigf, const float* __restrict__ rgbf,
    const float* __restrict__ tfine, float* __restrict__ out)
{
  __shared__ float sTf[8][48], sSc[8][48], sSf[8][48];
  int ray0 = blockIdx.x*8;
  for (int t=threadIdx.x; t<8*48; t+=256){
    int rr = t/48, k = t - rr*48;
    int gr = ray0+rr;
    sTf[rr][k] = tfine[(size_t)gr*SF+k];
    sSc[rr][k] = sigc[(size_t)gr*SC+k];
    sSf[rr][k] = sigf[(size_t)gr*SF+k];
  }
  __syncthreads();
  int ch = threadIdx.x & 31;
  int rr = threadIdx.x >> 5;
  int ray = ray0 + rr;
  const float* cc = rgbc + (size_t)ray*SC*32 + ch;
  const float* cf = rgbf + (size_t)ray*SF*32 + ch;
  int i=0, j=0;
  float T=1.f, acc=0.f, dacc=0.f, wacc=0.f;
  float d_prev=0.f, s_prev=0.f, c_prev=0.f;
  #pragma unroll 1
  for (int step=0; step<96; step++){
    float dc = (i<48) ? (TC0 + (float)i*DTC) : 3.402823e38f;
    float df = (j<48) ? sTf[rr][j] : 3.402823e38f;
    float d, s, c;
    if (dc <= df){
      d = dc; s = sSc[rr][i]; c = cc[(size_t)i*32]; i++;
    } else {
      d = df; s = sSf[rr][j]; c = cf[(size_t)j*32]; j++;
    }
    if (step){
      float delta = d - d_prev;
      float dm = softplus_f(0.5f*(s_prev+s)-1.0f);
      float alpha = 1.0f - expf(-dm*delta);
      float w = alpha*T;
      T *= (1.0f - alpha + 1e-10f);
      acc  = fmaf(w*0.5f, c_prev+c, acc);
      dacc = fmaf(w*0.5f, d_prev+d, dacc);
      wacc += w;
    }
    d_prev=d; s_prev=s; c_prev=c;
  }
  out[(size_t)ray*32+ch] = 2.0f*acc - 1.0f;
  if (ch==0){
    out[OFF_DEPTH+ray] = dacc;
    out[OFF_WSUM+ray]  = wacc;
  }
}

extern "C" void kernel_launch(void* const* d_in, const int* in_sizes, int n_in,
                              void* d_out, int out_size, void* d_ws, size_t ws_size,
                              hipStream_t stream){
  const float* planes = (const float*)d_in[0];
  const float* orig   = (const float*)d_in[1];
  const float* dirs   = (const float*)d_in[2];
  const float* w1     = (const float*)d_in[3];
  const float* b1     = (const float*)d_in[4];
  const float* w2     = (const float*)d_in[5];
  const float* b2     = (const float*)d_in[6];
  float* out = (float*)d_out;
  float* ws  = (float*)d_ws;

  float* pT    = ws + PT_OFF;
  float* rgbc  = ws + RGBC_OFF;
  float* rgbf  = ws + RGBF_OFF;
  float* sigf  = ws + SIGF_OFF;
  float* tfine = ws + TFINE_OFF;

  // 1. transpose planes to channel-last
  k_transpose<<<dim3(NB*3*HPX*HPX/256), dim3(256), 0, stream>>>(planes, pT);
  // 2. coarse model eval (sigma -> d_out sdf region, rgb -> ws)
  k_model<true><<<dim3(NRAY*SC/256), dim3(256), 0, stream>>>(
      pT, orig, dirs, w1, b1, w2, b2, (const float*)nullptr, rgbc, out + OFF_SDF);
  // 3. coarse march + importance resample -> fine depths
  k_importance<<<dim3(NRAY/128), dim3(128), 0, stream>>>(out + OFF_SDF, tfine);
  // 4. fine model eval
  k_model<false><<<dim3(NRAY*SF/256), dim3(256), 0, stream>>>(
      pT, orig, dirs, w1, b1, w2, b2, tfine, rgbf, sigf);
  // 5. merge + final march -> rgb/depth/wsum
  k_final<<<dim3(NRAY*32/256), dim3(256), 0, stream>>>(
      out + OFF_SDF, rgbc, sigf, rgbf, tfine, out);
}

// Round 2
// 297.479 us; speedup vs baseline: 1.6866x; 1.6866x over previous
//
#include <hip/hip_runtime.h>
#include <cstddef>

#define NB 2
#define RPB 4096
#define NRAY (NB*RPB)          // 8192
#define SC 48
#define SF 48
#define CP 32
#define HPX 256
#define HID 64
#define NOUT 33

#define DTC (1.05f/47.0f)
#define TC0 (2.25f + 0.5f*(1.05f/47.0f))

// d_out layout (floats)
#define OFF_DEPTH (NRAY*32)            // 262144
#define OFF_WSUM  (OFF_DEPTH + NRAY)   // 270336
#define OFF_SDF   (OFF_WSUM + NRAY)    // 278528

// ws layout (floats)
#define PT_OFF    0
#define PT_SIZE   ((size_t)NB*3*HPX*HPX*CP)          // 12,582,912
#define RGBC_OFF  (PT_SIZE)
#define RGBF_OFF  (RGBC_OFF + (size_t)NRAY*SC*32)
#define SIGF_OFF  (RGBF_OFF + (size_t)NRAY*SF*32)
#define TFINE_OFF (SIGF_OFF + (size_t)NRAY*SF)
#define W1T_OFF   (TFINE_OFF + (size_t)NRAY*SF)      // 64*32 floats

// ---- fast transcendentals (hw v_exp_f32 / v_log_f32 / v_rcp_f32) ----
#define LOG2E 1.44269504f
#define LN2   0.69314718f
static __device__ __forceinline__ float fast_exp(float x){
  return __builtin_amdgcn_exp2f(x*LOG2E);
}
static __device__ __forceinline__ float softplus_f(float x){
  float e = __builtin_amdgcn_exp2f(-fabsf(x)*LOG2E);   // exp(-|x|) in (0,1]
  float l = __builtin_amdgcn_logf(1.0f + e)*LN2;       // log1p(e)
  return fmaxf(x, 0.0f) + l;
}
static __device__ __forceinline__ float fast_sigmoid_scaled(float a){
  float e = __builtin_amdgcn_exp2f(-a*LOG2E);
  return __builtin_amdgcn_rcpf(1.0f + e)*1.002f - 0.001f;
}

// planes (b,pl,c,y,x) -> planesT (b,pl,y,x,c)
__global__ __launch_bounds__(256) void k_transpose(const float* __restrict__ src,
                                                   float* __restrict__ dst){
  int idx = blockIdx.x*256 + threadIdx.x;      // over NB*3*HPX*HPX = 393216
  int xy = idx & (HPX*HPX-1);
  int bp = idx >> 16;
  const float* s = src + (size_t)bp*CP*HPX*HPX + xy;
  float v[CP];
  #pragma unroll
  for (int c=0;c<CP;c++) v[c] = s[(size_t)c*HPX*HPX];
  float4* d4 = reinterpret_cast<float4*>(dst + (size_t)idx*CP);
  #pragma unroll
  for (int c=0;c<CP;c+=4) d4[c>>2] = make_float4(v[c],v[c+1],v[c+2],v[c+3]);
}

// w1 (32x64) -> w1T (64x32) scaled by 1/3 (folds the plane-mean)
__global__ __launch_bounds__(256) void k_prep(const float* __restrict__ w1,
                                              float* __restrict__ w1T){
  int idx = blockIdx.x*256 + threadIdx.x;   // 2048
  int i = idx >> 5, c = idx & 31;
  w1T[i*CP + c] = w1[c*HID + i] * (1.0f/3.0f);
}

template<bool COARSE>
__global__ __launch_bounds__(256, 4) void k_model(
    const float* __restrict__ pT,
    const float* __restrict__ orig,
    const float* __restrict__ dirs,
    const float* __restrict__ w1T,
    const float* __restrict__ b1,
    const float* __restrict__ w2,
    const float* __restrict__ b2,
    const float* __restrict__ tfine,
    float* __restrict__ rgb_out,
    float* __restrict__ sig_out)
{
  int p = blockIdx.x*256 + threadIdx.x;        // point index, grid exact
  int ray = p / 48;
  int k = p - ray*48;
  int b = ray >> 12;                           // ray / 4096
  float t = COARSE ? (TC0 + (float)k*DTC) : tfine[p];
  float ox = orig[ray*3+0], oy = orig[ray*3+1], oz = orig[ray*3+2];
  float dx = dirs[ray*3+0], dy = dirs[ray*3+1], dz = dirs[ray*3+2];
  float cx = fmaf(t,dx,ox), cy = fmaf(t,dy,oy), cz = fmaf(t,dz,oz);

  float feat[CP];
  #pragma unroll
  for (int c=0;c<CP;c++) feat[c]=0.f;

  #pragma unroll
  for (int pl=0; pl<3; pl++){
    // plane 0: (x,y); plane 1: (x,z); plane 2: (z,x)
    float u = (pl==2)? cz : cx;
    float v = (pl==0)? cy : (pl==1 ? cz : cx);
    float x = ((u+1.0f)*256.0f - 1.0f)*0.5f;
    float y = ((v+1.0f)*256.0f - 1.0f)*0.5f;
    float xf = floorf(x), yf = floorf(y);
    float wx = x-xf, wy = y-yf;
    int ix = (int)xf, iy = (int)yf;
    const float* base = pT + ((size_t)(b*3+pl))*HPX*HPX*CP;
    float cw0 = (1.f-wx)*(1.f-wy), cw1 = wx*(1.f-wy), cw2 = (1.f-wx)*wy, cw3 = wx*wy;
    const int cxo[4] = {0,1,0,1};
    const int cyo[4] = {0,0,1,1};
    const float cww[4] = {cw0,cw1,cw2,cw3};
    #pragma unroll
    for (int corner=0; corner<4; corner++){
      int xi = ix + cxo[corner];
      int yi = iy + cyo[corner];
      if (xi>=0 && xi<HPX && yi>=0 && yi<HPX){
        const float4* q4 = reinterpret_cast<const float4*>(base + ((size_t)yi*HPX+xi)*CP);
        float wgt = cww[corner];
        #pragma unroll
        for (int q=0;q<8;q++){
          float4 f = q4[q];
          feat[q*4+0] = fmaf(wgt, f.x, feat[q*4+0]);
          feat[q*4+1] = fmaf(wgt, f.y, feat[q*4+1]);
          feat[q*4+2] = fmaf(wgt, f.z, feat[q*4+2]);
          feat[q*4+3] = fmaf(wgt, f.w, feat[q*4+3]);
        }
      }
    }
  }

  // fused MLP: out[33] accumulated per hidden unit; no h[64] array -> no spill
  float o[NOUT];
  #pragma unroll
  for (int j=0;j<NOUT;j++) o[j] = b2[j];

  #pragma unroll 4
  for (int i=0;i<HID;i++){
    float a = b1[i];
    #pragma unroll
    for (int c=0;c<CP;c++) a = fmaf(feat[c], w1T[i*CP+c], a);
    float s = softplus_f(a);
    #pragma unroll
    for (int j=0;j<NOUT;j++) o[j] = fmaf(s, w2[i*NOUT+j], o[j]);
  }

  sig_out[p] = o[0];
  float* rp = rgb_out + (size_t)p*32;
  #pragma unroll
  for (int j=0;j<32;j+=4){
    float4 vv;
    vv.x = fast_sigmoid_scaled(o[1+j+0]);
    vv.y = fast_sigmoid_scaled(o[1+j+1]);
    vv.z = fast_sigmoid_scaled(o[1+j+2]);
    vv.w = fast_sigmoid_scaled(o[1+j+3]);
    *reinterpret_cast<float4*>(rp+j) = vv;
  }
}

// coarse march -> weights -> importance CDF resample -> fine depths
__global__ __launch_bounds__(128) void k_importance(const float* __restrict__ sg_all,
                                                    float* __restrict__ tfine){
  __shared__ float sC[128][46];
  int tid = threadIdx.x;
  int ray = blockIdx.x*128 + tid;
  const float* sg = sg_all + (size_t)ray*SC;
  float T = 1.0f;
  float sum = 0.0f;
  float s_prev = sg[0];
  float wm1 = 0.f, wm2 = 0.f;
  for (int k=0;k<47;k++){
    float s_next = sg[k+1];
    float dm = softplus_f(0.5f*(s_prev+s_next)-1.0f);
    float alpha = 1.0f - fast_exp(-dm*DTC);
    float wk = alpha*T;
    T *= (1.0f - alpha + 1e-10f);
    s_prev = s_next;
    if (k>=2){
      float q = 0.5f*(fmaxf(wm2,wm1)+fmaxf(wm1,wk)) + 0.01f;
      sC[tid][k-1] = q;
      sum += q;
    }
    wm2 = wm1; wm1 = wk;
  }
  sC[tid][0] = 0.0f;
  float run = 0.0f;
  float rsum = 1.0f/sum;
  for (int i=1;i<=45;i++){
    run += sC[tid][i]*rsum;
    sC[tid][i] = run;
  }
  float* tf = tfine + (size_t)ray*SF;
  int idx = 1;
  for (int j=0;j<48;j++){
    float u = (float)j/47.0f;
    while (idx<46 && sC[tid][idx] <= u) idx++;   // searchsorted right
    int below = idx-1;
    int above = (idx<46) ? idx : 45;
    float cb = sC[tid][below];
    float ca = sC[tid][above];
    float bb = TC0 + ((float)below+0.5f)*DTC;    // z_mid[below]
    float ba = TC0 + ((float)above+0.5f)*DTC;
    float denom = ca - cb;
    if (denom < 1e-5f) denom = 1.0f;
    tf[j] = bb + (u-cb)/denom*(ba-bb);
  }
}

// merge coarse+fine (stable, coarse first on tie) + final march; 32 lanes per ray
__global__ __launch_bounds__(256) void k_final(
    const float* __restrict__ sigc, const float* __restrict__ rgbc,
    const float* __restrict__ sigf, const float* __restrict__ rgbf,
    const float* __restrict__ tfine, float* __restrict__ out)
{
  __shared__ float sTf[8][48], sSc[8][48], sSf[8][48];
  int ray0 = blockIdx.x*8;
  for (int t=threadIdx.x; t<8*48; t+=256){
    int rr = t/48, k = t - rr*48;
    int gr = ray0+rr;
    sTf[rr][k] = tfine[(size_t)gr*SF+k];
    sSc[rr][k] = sigc[(size_t)gr*SC+k];
    sSf[rr][k] = sigf[(size_t)gr*SF+k];
  }
  __syncthreads();
  int ch = threadIdx.x & 31;
  int rr = threadIdx.x >> 5;
  int ray = ray0 + rr;
  const float* cc = rgbc + (size_t)ray*SC*32 + ch;
  const float* cf = rgbf + (size_t)ray*SF*32 + ch;
  int i=0, j=0;
  float T=1.f, acc=0.f, dacc=0.f, wacc=0.f;
  float d_prev=0.f, s_prev=0.f, c_prev=0.f;
  #pragma unroll 1
  for (int step=0; step<96; step++){
    float dc = (i<48) ? (TC0 + (float)i*DTC) : 3.402823e38f;
    float df = (j<48) ? sTf[rr][j] : 3.402823e38f;
    float d, s, c;
    if (dc <= df){
      d = dc; s = sSc[rr][i]; c = cc[(size_t)i*32]; i++;
    } else {
      d = df; s = sSf[rr][j]; c = cf[(size_t)j*32]; j++;
    }
    if (step){
      float delta = d - d_prev;
      float dm = softplus_f(0.5f*(s_prev+s)-1.0f);
      float alpha = 1.0f - fast_exp(-dm*delta);
      float w = alpha*T;
      T *= (1.0f - alpha + 1e-10f);
      acc  = fmaf(w*0.5f, c_prev+c, acc);
      dacc = fmaf(w*0.5f, d_prev+d, dacc);
      wacc += w;
    }
    d_prev=d; s_prev=s; c_prev=c;
  }
  out[(size_t)ray*32+ch] = 2.0f*acc - 1.0f;
  if (ch==0){
    out[OFF_DEPTH+ray] = dacc;
    out[OFF_WSUM+ray]  = wacc;
  }
}

extern "C" void kernel_launch(void* const* d_in, const int* in_sizes, int n_in,
                              void* d_out, int out_size, void* d_ws, size_t ws_size,
                              hipStream_t stream){
  const float* planes = (const float*)d_in[0];
  const float* orig   = (const float*)d_in[1];
  const float* dirs   = (const float*)d_in[2];
  const float* w1     = (const float*)d_in[3];
  const float* b1     = (const float*)d_in[4];
  const float* w2     = (const float*)d_in[5];
  const float* b2     = (const float*)d_in[6];
  float* out = (float*)d_out;
  float* ws  = (float*)d_ws;

  float* pT    = ws + PT_OFF;
  float* rgbc  = ws + RGBC_OFF;
  float* rgbf  = ws + RGBF_OFF;
  float* sigf  = ws + SIGF_OFF;
  float* tfine = ws + TFINE_OFF;
  float* w1T   = ws + W1T_OFF;

  // 1. transpose planes to channel-last; prep transposed+scaled w1
  k_transpose<<<dim3(NB*3*HPX*HPX/256), dim3(256), 0, stream>>>(planes, pT);
  k_prep<<<dim3(8), dim3(256), 0, stream>>>(w1, w1T);
  // 2. coarse model eval (sigma -> d_out sdf region, rgb -> ws)
  k_model<true><<<dim3(NRAY*SC/256), dim3(256), 0, stream>>>(
      pT, orig, dirs, w1T, b1, w2, b2, (const float*)nullptr, rgbc, out + OFF_SDF);
  // 3. coarse march + importance resample -> fine depths
  k_importance<<<dim3(NRAY/128), dim3(128), 0, stream>>>(out + OFF_SDF, tfine);
  // 4. fine model eval
  k_model<false><<<dim3(NRAY*SF/256), dim3(256), 0, stream>>>(
      pT, orig, dirs, w1T, b1, w2, b2, tfine, rgbf, sigf);
  // 5. merge + final march -> rgb/depth/wsum
  k_final<<<dim3(NRAY*32/256), dim3(256), 0, stream>>>(
      out + OFF_SDF, rgbc, sigf, rgbf, tfine, out);
}

// Round 3
// 167.521 us; speedup vs baseline: 2.9950x; 1.7758x over previous
//
#include <hip/hip_runtime.h>
#include <cstddef>

#define NB 2
#define RPB 4096
#define NRAY (NB*RPB)          // 8192
#define SC 48
#define SF 48
#define CP 32
#define HPX 256
#define HID 64
#define NOUT 33

#define DTC (1.05f/47.0f)
#define TC0 (2.25f + 0.5f*(1.05f/47.0f))

// d_out layout (floats)
#define OFF_DEPTH (NRAY*32)            // 262144
#define OFF_WSUM  (OFF_DEPTH + NRAY)   // 270336
#define OFF_SDF   (OFF_WSUM + NRAY)    // 278528

// ws layout (BYTES)
#define PT_B     ((size_t)0)                    // planesT f16: 2*3*256*256*32 = 12.58M f16
#define RGBC_B   ((size_t)25165824)             // rgb coarse f16: 8192*48*32
#define RGBF_B   ((size_t)50331648)             // rgb fine  f16
#define SIGF_B   ((size_t)75497472)             // sigma fine f32: 8192*48
#define TFINE_B  ((size_t)77070336)             // fine depths f32
#define W1A_B    ((size_t)78643200)             // w1 A-frags f16: 4*64*8
#define B1F_B    ((size_t)78647296)             // b1 frags f32: 4*64*4
#define W2A_B    ((size_t)78651392)             // w2 A-frags f16: 6*64*8
#define B2F_B    ((size_t)78657536)             // b2 frags f32: 3*64*4

typedef _Float16 f16;
typedef _Float16 f16x2 __attribute__((ext_vector_type(2)));
typedef _Float16 f16x8 __attribute__((ext_vector_type(8)));
typedef float    f32x4 __attribute__((ext_vector_type(4)));

#define LOG2E 1.44269504f
#define LN2   0.69314718f
static __device__ __forceinline__ float fast_exp(float x){
  return __builtin_amdgcn_exp2f(x*LOG2E);
}
static __device__ __forceinline__ float softplus_f(float x){
  float e = __builtin_amdgcn_exp2f(-fabsf(x)*LOG2E);
  float l = __builtin_amdgcn_logf(1.0f + e)*LN2;
  return fmaxf(x, 0.0f) + l;
}
static __device__ __forceinline__ float fast_sigmoid_scaled(float a){
  float e = __builtin_amdgcn_exp2f(-a*LOG2E);
  return __builtin_amdgcn_rcpf(1.0f + e)*1.002f - 0.001f;
}

// planes (b,pl,c,y,x) f32 -> planesT (b,pl,y,x,c) f16
__global__ __launch_bounds__(256) void k_transpose(const float* __restrict__ src,
                                                   f16* __restrict__ dst){
  int idx = blockIdx.x*256 + threadIdx.x;      // over NB*3*HPX*HPX = 393216
  int xy = idx & (HPX*HPX-1);
  int bp = idx >> 16;
  const float* s = src + (size_t)bp*CP*HPX*HPX + xy;
  unsigned int w[16];
  #pragma unroll
  for (int c=0;c<CP;c+=2){
    f16x2 h2 = { (f16)s[(size_t)c*HPX*HPX], (f16)s[(size_t)(c+1)*HPX*HPX] };
    w[c>>1] = __builtin_bit_cast(unsigned int, h2);
  }
  uint4* d4 = reinterpret_cast<uint4*>(dst + (size_t)idx*CP);
  d4[0] = make_uint4(w[0],w[1],w[2],w[3]);
  d4[1] = make_uint4(w[4],w[5],w[6],w[7]);
  d4[2] = make_uint4(w[8],w[9],w[10],w[11]);
  d4[3] = make_uint4(w[12],w[13],w[14],w[15]);
}

// Build MFMA fragments for w1 (scaled 1/3), w2 (row-permuted: rows 0..31=rgb ch,
// row 32=sigma, 33..47=0) and bias frags matching C-layout row=(l>>4)*4+r.
__global__ __launch_bounds__(256) void k_prep(const float* __restrict__ w1,
                                              const float* __restrict__ b1,
                                              const float* __restrict__ w2,
                                              const float* __restrict__ b2,
                                              f16* __restrict__ w1A,
                                              float* __restrict__ b1F,
                                              f16* __restrict__ w2A,
                                              float* __restrict__ b2F){
  int tid = threadIdx.x;
  {
    int m = tid>>6, lane = tid&63, q = lane>>4, r16 = lane&15;
    #pragma unroll
    for (int j=0;j<8;j++){
      int c = q*8+j, i = m*16+r16;
      w1A[(m*64+lane)*8+j] = (f16)(w1[c*HID+i]*(1.0f/3.0f));
    }
    #pragma unroll
    for (int r=0;r<4;r++) b1F[(m*64+lane)*4+r] = b1[m*16+q*4+r];
  }
  for (int idx=tid; idx<384; idx+=256){
    int f = idx>>6, lane = idx&63, q = lane>>4, r16 = lane&15;
    int kc = f/3, m2 = f - kc*3;
    int row = m2*16+r16;
    int col = (row<32)? (row+1) : ((row==32)? 0 : -1);
    #pragma unroll
    for (int j=0;j<8;j++){
      int k = kc*32+q*8+j;
      w2A[(f*64+lane)*8+j] = (col>=0)? (f16)w2[k*NOUT+col] : (f16)0.0f;
    }
  }
  if (tid<192){
    int m2 = tid>>6, lane = tid&63, q = lane>>4;
    #pragma unroll
    for (int r=0;r<4;r++){
      int row = m2*16+q*4+r;
      float v = (row<32)? b2[row+1] : ((row==32)? b2[0] : 0.0f);
      b2F[(m2*64+lane)*4+r] = v;
    }
  }
}

template<bool COARSE>
__global__ __launch_bounds__(256, 4) void k_model(
    const f16* __restrict__ pT,
    const float* __restrict__ orig,
    const float* __restrict__ dirs,
    const uint4* __restrict__ w1A,
    const f32x4* __restrict__ b1F,
    const uint4* __restrict__ w2A,
    const f32x4* __restrict__ b2F,
    const float* __restrict__ tfine,
    f16* __restrict__ rgb_out,
    float* __restrict__ sig_out)
{
  __shared__ unsigned int lds[4][2304];   // 9216 B per wave, wave-private
  int tid = threadIdx.x;
  int lane = tid & 63;
  int wv = tid >> 6;
  int q = lane >> 4;
  int c16 = lane & 15;
  unsigned int* fb = &lds[wv][0];

  // ---- phase 1: per-lane gather of feat (f16x2 packed) ----
  int p = blockIdx.x*256 + tid;
  {
    int ray = p / 48;
    int kk = p - ray*48;
    int b = ray >> 12;
    float t = COARSE ? (TC0 + (float)kk*DTC) : tfine[p];
    float ox = orig[ray*3+0], oy = orig[ray*3+1], oz = orig[ray*3+2];
    float dx = dirs[ray*3+0], dy = dirs[ray*3+1], dz = dirs[ray*3+2];
    float cx = fmaf(t,dx,ox), cy = fmaf(t,dy,oy), cz = fmaf(t,dz,oz);

    f16x2 feat2[16];
    #pragma unroll
    for (int i=0;i<16;i++) feat2[i] = (f16x2){(f16)0.0f,(f16)0.0f};

    #pragma unroll
    for (int pl=0; pl<3; pl++){
      float u = (pl==2)? cz : cx;
      float v = (pl==0)? cy : (pl==1 ? cz : cx);
      float x = ((u+1.0f)*256.0f - 1.0f)*0.5f;
      float y = ((v+1.0f)*256.0f - 1.0f)*0.5f;
      float xf = floorf(x), yf = floorf(y);
      float wx = x-xf, wy = y-yf;
      int ix = (int)xf, iy = (int)yf;
      const f16* base = pT + ((size_t)(b*3+pl))*HPX*HPX*CP;
      const float cww[4] = {(1.f-wx)*(1.f-wy), wx*(1.f-wy), (1.f-wx)*wy, wx*wy};
      const int cxo[4] = {0,1,0,1};
      const int cyo[4] = {0,0,1,1};
      #pragma unroll
      for (int corner=0; corner<4; corner++){
        int xi = ix + cxo[corner];
        int yi = iy + cyo[corner];
        if (xi>=0 && xi<HPX && yi>=0 && yi<HPX){
          const uint4* q4 = reinterpret_cast<const uint4*>(base + ((size_t)(yi*HPX+xi))*CP);
          uint4 u0 = q4[0], u1 = q4[1], u2 = q4[2], u3 = q4[3];
          f16 wh = (f16)cww[corner];
          f16x2 wv2 = {wh, wh};
          unsigned int uu[16] = {u0.x,u0.y,u0.z,u0.w, u1.x,u1.y,u1.z,u1.w,
                                 u2.x,u2.y,u2.z,u2.w, u3.x,u3.y,u3.z,u3.w};
          #pragma unroll
          for (int i=0;i<16;i++)
            feat2[i] += __builtin_bit_cast(f16x2, uu[i]) * wv2;
        }
      }
    }
    // write feat to LDS: point lane, stride 18 uints (72 B)
    int po = lane*18;
    #pragma unroll
    for (int i=0;i<8;i++){
      uint2 v2;
      v2.x = __builtin_bit_cast(unsigned int, feat2[2*i]);
      v2.y = __builtin_bit_cast(unsigned int, feat2[2*i+1]);
      *reinterpret_cast<uint2*>(&fb[po + 2*i]) = v2;
    }
  }

  // ---- phase 2: GEMM1'  C[hidden 64][point 64] = w1'(A) x feat(B) ----
  f32x4 acc1[4][4];
  #pragma unroll
  for (int m=0;m<4;m++){
    f32x4 binit = b1F[m*64+lane];
    #pragma unroll
    for (int n=0;n<4;n++) acc1[m][n] = binit;
  }
  f16x8 bfr[4];
  #pragma unroll
  for (int n=0;n<4;n++){
    int P = n*16 + c16;
    uint2 lo = *reinterpret_cast<const uint2*>(&fb[P*18 + q*4]);
    uint2 hi = *reinterpret_cast<const uint2*>(&fb[P*18 + q*4 + 2]);
    uint4 u = make_uint4(lo.x, lo.y, hi.x, hi.y);
    bfr[n] = __builtin_bit_cast(f16x8, u);
  }
  #pragma unroll
  for (int m=0;m<4;m++){
    f16x8 a = __builtin_bit_cast(f16x8, w1A[m*64+lane]);
    #pragma unroll
    for (int n=0;n<4;n++)
      acc1[m][n] = __builtin_amdgcn_mfma_f32_16x16x32_f16(a, bfr[n], acc1[m][n], 0,0,0);
  }

  // ---- phase 3: softplus -> h (f16) -> LDS [point][hidden], stride 36 uints ----
  #pragma unroll
  for (int m=0;m<4;m++){
    #pragma unroll
    for (int n=0;n<4;n++){
      f32x4 v = acc1[m][n];
      f16x2 h0 = { (f16)softplus_f(v[0]), (f16)softplus_f(v[1]) };
      f16x2 h1 = { (f16)softplus_f(v[2]), (f16)softplus_f(v[3]) };
      int P = n*16 + c16;
      uint2 v2;
      v2.x = __builtin_bit_cast(unsigned int, h0);
      v2.y = __builtin_bit_cast(unsigned int, h1);
      *reinterpret_cast<uint2*>(&fb[P*36 + m*8 + q*2]) = v2;
    }
  }

  // ---- phase 4: GEMM2'  C[out 48][point 64] = w2'(A) x h(B) ----
  f32x4 acc2[3][4];
  #pragma unroll
  for (int m2=0;m2<3;m2++){
    f32x4 binit = b2F[m2*64+lane];
    #pragma unroll
    for (int n=0;n<4;n++) acc2[m2][n] = binit;
  }
  f16x8 b2fr[2][4];
  #pragma unroll
  for (int kc=0;kc<2;kc++){
    #pragma unroll
    for (int n=0;n<4;n++){
      int P = n*16 + c16;
      uint4 u = *reinterpret_cast<const uint4*>(&fb[P*36 + kc*16 + q*4]);
      b2fr[kc][n] = __builtin_bit_cast(f16x8, u);
    }
  }
  #pragma unroll
  for (int kc=0;kc<2;kc++){
    #pragma unroll
    for (int m2=0;m2<3;m2++){
      f16x8 a = __builtin_bit_cast(f16x8, w2A[(kc*3+m2)*64+lane]);
      #pragma unroll
      for (int n=0;n<4;n++)
        acc2[m2][n] = __builtin_amdgcn_mfma_f32_16x16x32_f16(a, b2fr[kc][n], acc2[m2][n], 0,0,0);
    }
  }

  // ---- phase 5: outputs. rows 0..31 = rgb channels (4-aligned), row 32 = sigma ----
  int pbase = blockIdx.x*256 + wv*64;
  #pragma unroll
  for (int n=0;n<4;n++){
    int P = pbase + n*16 + c16;
    #pragma unroll
    for (int m2=0;m2<2;m2++){
      f32x4 v = acc2[m2][n];
      f16x2 u0 = { (f16)fast_sigmoid_scaled(v[0]), (f16)fast_sigmoid_scaled(v[1]) };
      f16x2 u1 = { (f16)fast_sigmoid_scaled(v[2]), (f16)fast_sigmoid_scaled(v[3]) };
      int ch = m2*16 + q*4;
      uint2 v2;
      v2.x = __builtin_bit_cast(unsigned int, u0);
      v2.y = __builtin_bit_cast(unsigned int, u1);
      *reinterpret_cast<uint2*>(rgb_out + (size_t)P*32 + ch) = v2;
    }
    if (q==0) sig_out[P] = acc2[2][n][0];
  }
}

// coarse march -> weights -> importance CDF resample -> fine depths
__global__ __launch_bounds__(128) void k_importance(const float* __restrict__ sg_all,
                                                    float* __restrict__ tfine){
  __shared__ float sC[128][46];
  int tid = threadIdx.x;
  int ray = blockIdx.x*128 + tid;
  const float* sg = sg_all + (size_t)ray*SC;
  float T = 1.0f;
  float sum = 0.0f;
  float s_prev = sg[0];
  float wm1 = 0.f, wm2 = 0.f;
  for (int k=0;k<47;k++){
    float s_next = sg[k+1];
    float dm = softplus_f(0.5f*(s_prev+s_next)-1.0f);
    float alpha = 1.0f - fast_exp(-dm*DTC);
    float wk = alpha*T;
    T *= (1.0f - alpha + 1e-10f);
    s_prev = s_next;
    if (k>=2){
      float qv = 0.5f*(fmaxf(wm2,wm1)+fmaxf(wm1,wk)) + 0.01f;
      sC[tid][k-1] = qv;
      sum += qv;
    }
    wm2 = wm1; wm1 = wk;
  }
  sC[tid][0] = 0.0f;
  float run = 0.0f;
  float rsum = 1.0f/sum;
  for (int i=1;i<=45;i++){
    run += sC[tid][i]*rsum;
    sC[tid][i] = run;
  }
  float* tf = tfine + (size_t)ray*SF;
  int idx = 1;
  for (int j=0;j<48;j++){
    float u = (float)j/47.0f;
    while (idx<46 && sC[tid][idx] <= u) idx++;   // searchsorted right
    int below = idx-1;
    int above = (idx<46) ? idx : 45;
    float cb = sC[tid][below];
    float ca = sC[tid][above];
    float bb = TC0 + ((float)below+0.5f)*DTC;
    float ba = TC0 + ((float)above+0.5f)*DTC;
    float denom = ca - cb;
    if (denom < 1e-5f) denom = 1.0f;
    tf[j] = bb + (u-cb)/denom*(ba-bb);
  }
}

// merge coarse+fine (stable, coarse first on tie) + final march; 32 lanes per ray
__global__ __launch_bounds__(256) void k_final(
    const float* __restrict__ sigc, const f16* __restrict__ rgbc,
    const float* __restrict__ sigf, const f16* __restrict__ rgbf,
    const float* __restrict__ tfine, float* __restrict__ out)
{
  __shared__ float sTf[8][48], sSc[8][48], sSf[8][48];
  int ray0 = blockIdx.x*8;
  for (int t=threadIdx.x; t<8*48; t+=256){
    int rr = t/48, k = t - rr*48;
    int gr = ray0+rr;
    sTf[rr][k] = tfine[(size_t)gr*SF+k];
    sSc[rr][k] = sigc[(size_t)gr*SC+k];
    sSf[rr][k] = sigf[(size_t)gr*SF+k];
  }
  __syncthreads();
  int ch = threadIdx.x & 31;
  int rr = threadIdx.x >> 5;
  int ray = ray0 + rr;
  const f16* cc = rgbc + (size_t)ray*SC*32 + ch;
  const f16* cf = rgbf + (size_t)ray*SF*32 + ch;
  int i=0, j=0;
  float T=1.f, acc=0.f, dacc=0.f, wacc=0.f;
  float d_prev=0.f, s_prev=0.f, c_prev=0.f;
  #pragma unroll 1
  for (int step=0; step<96; step++){
    float dc = (i<48) ? (TC0 + (float)i*DTC) : 3.402823e38f;
    float df = (j<48) ? sTf[rr][j] : 3.402823e38f;
    float d, s, c;
    if (dc <= df){
      d = dc; s = sSc[rr][i]; c = (float)cc[(size_t)i*32]; i++;
    } else {
      d = df; s = sSf[rr][j]; c = (float)cf[(size_t)j*32]; j++;
    }
    if (step){
      float delta = d - d_prev;
      float dm = softplus_f(0.5f*(s_prev+s)-1.0f);
      float alpha = 1.0f - fast_exp(-dm*delta);
      float w = alpha*T;
      T *= (1.0f - alpha + 1e-10f);
      acc  = fmaf(w*0.5f, c_prev+c, acc);
      dacc = fmaf(w*0.5f, d_prev+d, dacc);
      wacc += w;
    }
    d_prev=d; s_prev=s; c_prev=c;
  }
  out[(size_t)ray*32+ch] = 2.0f*acc - 1.0f;
  if (ch==0){
    out[OFF_DEPTH+ray] = dacc;
    out[OFF_WSUM+ray]  = wacc;
  }
}

extern "C" void kernel_launch(void* const* d_in, const int* in_sizes, int n_in,
                              void* d_out, int out_size, void* d_ws, size_t ws_size,
                              hipStream_t stream){
  const float* planes = (const float*)d_in[0];
  const float* orig   = (const float*)d_in[1];
  const float* dirs   = (const float*)d_in[2];
  const float* w1     = (const float*)d_in[3];
  const float* b1     = (const float*)d_in[4];
  const float* w2     = (const float*)d_in[5];
  const float* b2     = (const float*)d_in[6];
  float* out = (float*)d_out;
  char*  ws  = (char*)d_ws;

  f16*   pT    = (f16*)(ws + PT_B);
  f16*   rgbc  = (f16*)(ws + RGBC_B);
  f16*   rgbf  = (f16*)(ws + RGBF_B);
  float* sigf  = (float*)(ws + SIGF_B);
  float* tfine = (float*)(ws + TFINE_B);
  f16*   w1A   = (f16*)(ws + W1A_B);
  float* b1F   = (float*)(ws + B1F_B);
  f16*   w2A   = (f16*)(ws + W2A_B);
  float* b2F   = (float*)(ws + B2F_B);

  k_transpose<<<dim3(NB*3*HPX*HPX/256), dim3(256), 0, stream>>>(planes, pT);
  k_prep<<<dim3(1), dim3(256), 0, stream>>>(w1, b1, w2, b2, w1A, b1F, w2A, b2F);
  k_model<true><<<dim3(NRAY*SC/256), dim3(256), 0, stream>>>(
      pT, orig, dirs, (const uint4*)w1A, (const f32x4*)b1F, (const uint4*)w2A,
      (const f32x4*)b2F, (const float*)nullptr, rgbc, out + OFF_SDF);
  k_importance<<<dim3(NRAY/128), dim3(128), 0, stream>>>(out + OFF_SDF, tfine);
  k_model<false><<<dim3(NRAY*SF/256), dim3(256), 0, stream>>>(
      pT, orig, dirs, (const uint4*)w1A, (const f32x4*)b1F, (const uint4*)w2A,
      (const f32x4*)b2F, tfine, rgbf, sigf);
  k_final<<<dim3(NRAY*32/256), dim3(256), 0, stream>>>(
      out + OFF_SDF, rgbc, sigf, rgbf, tfine, out);
}

// Round 4
// 140.009 us; speedup vs baseline: 3.5835x; 1.1965x over previous
//
#include <hip/hip_runtime.h>
#include <cstddef>

#define NB 2
#define RPB 4096
#define NRAY (NB*RPB)          // 8192
#define SC 48
#define SF 48
#define CP 32
#define HPX 256
#define HID 64
#define NOUT 33

#define DTC (1.05f/47.0f)
#define TC0 (2.25f + 0.5f*(1.05f/47.0f))

// d_out layout (floats)
#define OFF_DEPTH (NRAY*32)            // 262144
#define OFF_WSUM  (OFF_DEPTH + NRAY)   // 270336
#define OFF_SDF   (OFF_WSUM + NRAY)    // 278528

// ws layout (BYTES)
#define PT_B     ((size_t)0)                    // planesT f16
#define RGBC_B   ((size_t)25165824)             // rgb coarse f16: 8192*48*32
#define RGBF_B   ((size_t)50331648)             // rgb fine  f16
#define SIGF_B   ((size_t)75497472)             // sigma fine f32
#define TFINE_B  ((size_t)77070336)             // fine depths f32
#define W1A_B    ((size_t)78643200)
#define B1F_B    ((size_t)78647296)
#define W2A_B    ((size_t)78651392)
#define B2F_B    ((size_t)78657536)

typedef _Float16 f16;
typedef _Float16 f16x2 __attribute__((ext_vector_type(2)));
typedef _Float16 f16x8 __attribute__((ext_vector_type(8)));
typedef float    f32x4 __attribute__((ext_vector_type(4)));

#define LOG2E 1.44269504f
#define LN2   0.69314718f
static __device__ __forceinline__ float fast_exp(float x){
  return __builtin_amdgcn_exp2f(x*LOG2E);
}
static __device__ __forceinline__ float softplus_f(float x){
  float e = __builtin_amdgcn_exp2f(-fabsf(x)*LOG2E);
  float l = __builtin_amdgcn_logf(1.0f + e)*LN2;
  return fmaxf(x, 0.0f) + l;
}
static __device__ __forceinline__ float fast_sigmoid_scaled(float a){
  float e = __builtin_amdgcn_exp2f(-a*LOG2E);
  return __builtin_amdgcn_rcpf(1.0f + e)*1.002f - 0.001f;
}

// planes (b,pl,c,y,x) f32 -> planesT (b,pl,y,x,c) f16
__global__ __launch_bounds__(256) void k_transpose(const float* __restrict__ src,
                                                   f16* __restrict__ dst){
  int idx = blockIdx.x*256 + threadIdx.x;
  int xy = idx & (HPX*HPX-1);
  int bp = idx >> 16;
  const float* s = src + (size_t)bp*CP*HPX*HPX + xy;
  unsigned int w[16];
  #pragma unroll
  for (int c=0;c<CP;c+=2){
    f16x2 h2 = { (f16)s[(size_t)c*HPX*HPX], (f16)s[(size_t)(c+1)*HPX*HPX] };
    w[c>>1] = __builtin_bit_cast(unsigned int, h2);
  }
  uint4* d4 = reinterpret_cast<uint4*>(dst + (size_t)idx*CP);
  d4[0] = make_uint4(w[0],w[1],w[2],w[3]);
  d4[1] = make_uint4(w[4],w[5],w[6],w[7]);
  d4[2] = make_uint4(w[8],w[9],w[10],w[11]);
  d4[3] = make_uint4(w[12],w[13],w[14],w[15]);
}

// MFMA fragment prep (same as round 3)
__global__ __launch_bounds__(256) void k_prep(const float* __restrict__ w1,
                                              const float* __restrict__ b1,
                                              const float* __restrict__ w2,
                                              const float* __restrict__ b2,
                                              f16* __restrict__ w1A,
                                              float* __restrict__ b1F,
                                              f16* __restrict__ w2A,
                                              float* __restrict__ b2F){
  int tid = threadIdx.x;
  {
    int m = tid>>6, lane = tid&63, q = lane>>4, r16 = lane&15;
    #pragma unroll
    for (int j=0;j<8;j++){
      int c = q*8+j, i = m*16+r16;
      w1A[(m*64+lane)*8+j] = (f16)(w1[c*HID+i]*(1.0f/3.0f));
    }
    #pragma unroll
    for (int r=0;r<4;r++) b1F[(m*64+lane)*4+r] = b1[m*16+q*4+r];
  }
  for (int idx=tid; idx<384; idx+=256){
    int f = idx>>6, lane = idx&63, q = lane>>4, r16 = lane&15;
    int kc = f/3, m2 = f - kc*3;
    int row = m2*16+r16;
    int col = (row<32)? (row+1) : ((row==32)? 0 : -1);
    #pragma unroll
    for (int j=0;j<8;j++){
      int k = kc*32+q*8+j;
      w2A[(f*64+lane)*8+j] = (col>=0)? (f16)w2[k*NOUT+col] : (f16)0.0f;
    }
  }
  if (tid<192){
    int m2 = tid>>6, lane = tid&63, q = lane>>4;
    #pragma unroll
    for (int r=0;r<4;r++){
      int row = m2*16+q*4+r;
      float v = (row<32)? b2[row+1] : ((row==32)? b2[0] : 0.0f);
      b2F[(m2*64+lane)*4+r] = v;
    }
  }
}

template<bool COARSE>
__global__ __launch_bounds__(256) void k_model(
    const f16* __restrict__ pT,
    const float* __restrict__ orig,
    const float* __restrict__ dirs,
    const uint4* __restrict__ w1A,
    const f32x4* __restrict__ b1F,
    const uint4* __restrict__ w2A,
    const f32x4* __restrict__ b2F,
    const float* __restrict__ tfine,
    f16* __restrict__ rgb_out,
    float* __restrict__ sig_out)
{
  __shared__ unsigned int lds[4][2304];   // 9216 B per wave, wave-private
  int tid = threadIdx.x;
  int lane = tid & 63;
  int wv = tid >> 6;
  int q = lane >> 4;
  int c16 = lane & 15;
  unsigned int* fb = &lds[wv][0];

  // ---- phase 1: per-lane gather of feat (f16x2 packed), branchless ----
  int p = blockIdx.x*256 + tid;
  {
    int ray = p / 48;
    int kk = p - ray*48;
    int b = ray >> 12;
    float t = COARSE ? (TC0 + (float)kk*DTC) : tfine[p];
    float ox = orig[ray*3+0], oy = orig[ray*3+1], oz = orig[ray*3+2];
    float dx = dirs[ray*3+0], dy = dirs[ray*3+1], dz = dirs[ray*3+2];
    float cx = fmaf(t,dx,ox), cy = fmaf(t,dy,oy), cz = fmaf(t,dz,oz);

    f16x2 feat2[16];
    #pragma unroll
    for (int i=0;i<16;i++) feat2[i] = (f16x2){(f16)0.0f,(f16)0.0f};

    #pragma unroll
    for (int pl=0; pl<3; pl++){
      float u = (pl==2)? cz : cx;
      float v = (pl==0)? cy : (pl==1 ? cz : cx);
      float x = ((u+1.0f)*256.0f - 1.0f)*0.5f;
      float y = ((v+1.0f)*256.0f - 1.0f)*0.5f;
      float xf = floorf(x), yf = floorf(y);
      float wx = x-xf, wy = y-yf;
      int ix = (int)xf, iy = (int)yf;
      // clamped coords + validity-zeroed weights (branchless)
      int x0 = min(max(ix,0),HPX-1),   x1 = min(max(ix+1,0),HPX-1);
      int y0 = min(max(iy,0),HPX-1),   y1 = min(max(iy+1,0),HPX-1);
      float vx0 = ((unsigned)ix   < (unsigned)HPX) ? 1.f : 0.f;
      float vx1 = ((unsigned)(ix+1)<(unsigned)HPX) ? 1.f : 0.f;
      float vy0 = ((unsigned)iy   < (unsigned)HPX) ? 1.f : 0.f;
      float vy1 = ((unsigned)(iy+1)<(unsigned)HPX) ? 1.f : 0.f;
      float cw[4] = { (1.f-wx)*(1.f-wy)*vx0*vy0, wx*(1.f-wy)*vx1*vy0,
                      (1.f-wx)*wy*vx0*vy1,       wx*wy*vx1*vy1 };
      int off[4] = { (y0*HPX+x0)*4, (y0*HPX+x1)*4, (y1*HPX+x0)*4, (y1*HPX+x1)*4 };
      const uint4* b4 = reinterpret_cast<const uint4*>(pT + ((size_t)(b*3+pl))*HPX*HPX*CP);
      uint4 L[4][4];
      #pragma unroll
      for (int c=0;c<4;c++){
        #pragma unroll
        for (int qq=0;qq<4;qq++) L[c][qq] = b4[off[c]+qq];
      }
      #pragma unroll
      for (int c=0;c<4;c++){
        f16 wh = (f16)cw[c];
        f16x2 wv2 = {wh, wh};
        #pragma unroll
        for (int qq=0;qq<4;qq++){
          uint4 uu = L[c][qq];
          feat2[qq*4+0] += __builtin_bit_cast(f16x2, uu.x) * wv2;
          feat2[qq*4+1] += __builtin_bit_cast(f16x2, uu.y) * wv2;
          feat2[qq*4+2] += __builtin_bit_cast(f16x2, uu.z) * wv2;
          feat2[qq*4+3] += __builtin_bit_cast(f16x2, uu.w) * wv2;
        }
      }
    }
    int po = lane*18;
    #pragma unroll
    for (int i=0;i<8;i++){
      uint2 v2;
      v2.x = __builtin_bit_cast(unsigned int, feat2[2*i]);
      v2.y = __builtin_bit_cast(unsigned int, feat2[2*i+1]);
      *reinterpret_cast<uint2*>(&fb[po + 2*i]) = v2;
    }
  }

  // ---- phase 2: GEMM1' ----
  f32x4 acc1[4][4];
  #pragma unroll
  for (int m=0;m<4;m++){
    f32x4 binit = b1F[m*64+lane];
    #pragma unroll
    for (int n=0;n<4;n++) acc1[m][n] = binit;
  }
  f16x8 bfr[4];
  #pragma unroll
  for (int n=0;n<4;n++){
    int P = n*16 + c16;
    uint2 lo = *reinterpret_cast<const uint2*>(&fb[P*18 + q*4]);
    uint2 hi = *reinterpret_cast<const uint2*>(&fb[P*18 + q*4 + 2]);
    uint4 u = make_uint4(lo.x, lo.y, hi.x, hi.y);
    bfr[n] = __builtin_bit_cast(f16x8, u);
  }
  #pragma unroll
  for (int m=0;m<4;m++){
    f16x8 a = __builtin_bit_cast(f16x8, w1A[m*64+lane]);
    #pragma unroll
    for (int n=0;n<4;n++)
      acc1[m][n] = __builtin_amdgcn_mfma_f32_16x16x32_f16(a, bfr[n], acc1[m][n], 0,0,0);
  }

  // ---- phase 3: softplus -> h f16 -> LDS ----
  #pragma unroll
  for (int m=0;m<4;m++){
    #pragma unroll
    for (int n=0;n<4;n++){
      f32x4 v = acc1[m][n];
      f16x2 h0 = { (f16)softplus_f(v[0]), (f16)softplus_f(v[1]) };
      f16x2 h1 = { (f16)softplus_f(v[2]), (f16)softplus_f(v[3]) };
      int P = n*16 + c16;
      uint2 v2;
      v2.x = __builtin_bit_cast(unsigned int, h0);
      v2.y = __builtin_bit_cast(unsigned int, h1);
      *reinterpret_cast<uint2*>(&fb[P*36 + m*8 + q*2]) = v2;
    }
  }

  // ---- phase 4: GEMM2' ----
  f32x4 acc2[3][4];
  #pragma unroll
  for (int m2=0;m2<3;m2++){
    f32x4 binit = b2F[m2*64+lane];
    #pragma unroll
    for (int n=0;n<4;n++) acc2[m2][n] = binit;
  }
  f16x8 b2fr[2][4];
  #pragma unroll
  for (int kc=0;kc<2;kc++){
    #pragma unroll
    for (int n=0;n<4;n++){
      int P = n*16 + c16;
      uint4 u = *reinterpret_cast<const uint4*>(&fb[P*36 + kc*16 + q*4]);
      b2fr[kc][n] = __builtin_bit_cast(f16x8, u);
    }
  }
  #pragma unroll
  for (int kc=0;kc<2;kc++){
    #pragma unroll
    for (int m2=0;m2<3;m2++){
      f16x8 a = __builtin_bit_cast(f16x8, w2A[(kc*3+m2)*64+lane]);
      #pragma unroll
      for (int n=0;n<4;n++)
        acc2[m2][n] = __builtin_amdgcn_mfma_f32_16x16x32_f16(a, b2fr[kc][n], acc2[m2][n], 0,0,0);
    }
  }

  // ---- phase 5: outputs ----
  int pbase = blockIdx.x*256 + wv*64;
  #pragma unroll
  for (int n=0;n<4;n++){
    int P = pbase + n*16 + c16;
    #pragma unroll
    for (int m2=0;m2<2;m2++){
      f32x4 v = acc2[m2][n];
      f16x2 u0 = { (f16)fast_sigmoid_scaled(v[0]), (f16)fast_sigmoid_scaled(v[1]) };
      f16x2 u1 = { (f16)fast_sigmoid_scaled(v[2]), (f16)fast_sigmoid_scaled(v[3]) };
      int ch = m2*16 + q*4;
      uint2 v2;
      v2.x = __builtin_bit_cast(unsigned int, u0);
      v2.y = __builtin_bit_cast(unsigned int, u1);
      *reinterpret_cast<uint2*>(rgb_out + (size_t)P*32 + ch) = v2;
    }
    if (q==0) sig_out[P] = acc2[2][n][0];
  }
}

// coarse march -> importance CDF resample -> fine depths (unchanged)
__global__ __launch_bounds__(128) void k_importance(const float* __restrict__ sg_all,
                                                    float* __restrict__ tfine){
  __shared__ float sC[128][46];
  int tid = threadIdx.x;
  int ray = blockIdx.x*128 + tid;
  const float* sg = sg_all + (size_t)ray*SC;
  float T = 1.0f;
  float sum = 0.0f;
  float s_prev = sg[0];
  float wm1 = 0.f, wm2 = 0.f;
  for (int k=0;k<47;k++){
    float s_next = sg[k+1];
    float dm = softplus_f(0.5f*(s_prev+s_next)-1.0f);
    float alpha = 1.0f - fast_exp(-dm*DTC);
    float wk = alpha*T;
    T *= (1.0f - alpha + 1e-10f);
    s_prev = s_next;
    if (k>=2){
      float qv = 0.5f*(fmaxf(wm2,wm1)+fmaxf(wm1,wk)) + 0.01f;
      sC[tid][k-1] = qv;
      sum += qv;
    }
    wm2 = wm1; wm1 = wk;
  }
  sC[tid][0] = 0.0f;
  float run = 0.0f;
  float rsum = 1.0f/sum;
  for (int i=1;i<=45;i++){
    run += sC[tid][i]*rsum;
    sC[tid][i] = run;
  }
  float* tf = tfine + (size_t)ray*SF;
  int idx = 1;
  for (int j=0;j<48;j++){
    float u = (float)j/47.0f;
    while (idx<46 && sC[tid][idx] <= u) idx++;
    int below = idx-1;
    int above = (idx<46) ? idx : 45;
    float cb = sC[tid][below];
    float ca = sC[tid][above];
    float bb = TC0 + ((float)below+0.5f)*DTC;
    float ba = TC0 + ((float)above+0.5f)*DTC;
    float denom = ca - cb;
    if (denom < 1e-5f) denom = 1.0f;
    tf[j] = bb + (u-cb)/denom*(ba-bb);
  }
}

// wave-per-ray parallel merge + scan + march
// LDS slab words: DF 0..48, SC 48..96, SF 96..144, DM 144..240, SM 240..336,
// SRC 336..432, PART 432..2160 (48 rows x 36 words, 16B-aligned rows)
#define L_DF  0
#define L_SC  48
#define L_SF  96
#define L_DM  144
#define L_SM  240
#define L_SRC 336
#define L_PT  432
#define SLAB  2160

__global__ __launch_bounds__(256) void k_final(
    const float* __restrict__ sigc, const f16* __restrict__ rgbc,
    const float* __restrict__ sigf, const f16* __restrict__ rgbf,
    const float* __restrict__ tfine, float* __restrict__ out)
{
  __shared__ unsigned int slab[4][SLAB];
  int lane = threadIdx.x & 63;
  int wv = threadIdx.x >> 6;
  int ray = blockIdx.x*4 + wv;
  unsigned int* S = &slab[wv][0];
  float* Sf = (float*)S;

  if (lane < 48){
    Sf[L_DF+lane] = tfine[(size_t)ray*SF + lane];
    Sf[L_SC+lane] = sigc[(size_t)ray*SC + lane];
    Sf[L_SF+lane] = sigf[(size_t)ray*SF + lane];
  }

  if (lane < 48){
    // coarse elem i=lane: rank = i + #{fine < dc}
    float dcv = TC0 + (float)lane*DTC;
    int pos = 0;
    #pragma unroll
    for (int stp=32; stp>=1; stp>>=1){
      int np = pos + stp;
      if (np <= 48 && Sf[L_DF+np-1] < dcv) pos = np;
    }
    int rank_c = lane + pos;
    Sf[L_DM+rank_c] = dcv;
    Sf[L_SM+rank_c] = Sf[L_SC+lane];
    S [L_SRC+rank_c] = lane;
    // fine elem j=lane: rank = j + #{coarse <= df}
    float x = Sf[L_DF+lane];
    int cnt = (int)(floorf((x - TC0)*(1.0f/DTC)) + 1.0f);
    cnt = min(max(cnt,0),48);
    while (cnt < 48 && (TC0 + (float)cnt*DTC) <= x) cnt++;
    while (cnt > 0 && (TC0 + (float)(cnt-1)*DTC) > x) cnt--;
    int rank_f = lane + cnt;
    Sf[L_DM+rank_f] = x;
    Sf[L_SM+rank_f] = Sf[L_SF+lane];
    S [L_SRC+rank_f] = 48 + lane;
  }

  int s0 = 2*lane, s1 = 2*lane+1;
  float alpha0=0.f, alpha1=0.f, g0=1.f, g1=1.f;
  float d0=0.f, d1=0.f, d2=0.f;
  if (lane < 48){
    int s2i = min(s1+1, 95);
    d0 = Sf[L_DM+s0]; d1 = Sf[L_DM+s1]; d2 = Sf[L_DM+s2i];
    float m0 = Sf[L_SM+s0], m1 = Sf[L_SM+s1], m2 = Sf[L_SM+s2i];
    {
      float dm = softplus_f(0.5f*(m0+m1)-1.0f);
      alpha0 = 1.0f - fast_exp(-dm*(d1-d0));
      g0 = 1.0f - alpha0 + 1e-10f;
    }
    if (lane < 47){   // s1 < 95
      float dm = softplus_f(0.5f*(m1+m2)-1.0f);
      alpha1 = 1.0f - fast_exp(-dm*(d2-d1));
      g1 = 1.0f - alpha1 + 1e-10f;
    }
  }
  // inclusive product scan of (g0*g1) across lanes
  float ip = g0*g1;
  #pragma unroll
  for (int off=1; off<64; off<<=1){
    float v = __shfl_up(ip, off);
    if (lane >= off) ip *= v;
  }
  float E = __shfl_up(ip, 1);
  if (lane == 0) E = 1.0f;
  float w0 = alpha0*E;
  float w1 = alpha1*E*g0;
  float wprev = __shfl_up(w1, 1);
  if (lane == 0) wprev = 0.0f;
  float coef0 = 0.5f*(wprev + w0);
  float coef1 = 0.5f*(w0 + w1);
  float dp = (lane<48) ? (w0*0.5f*(d0+d1) + w1*0.5f*(d1+d2)) : 0.f;
  float wp = w0 + w1;

  if (lane < 48){
    int src0 = (int)S[L_SRC+s0], src1 = (int)S[L_SRC+s1];
    const f16* c0p = (src0<48) ? (rgbc + ((size_t)ray*SC + src0)*32)
                               : (rgbf + ((size_t)ray*SF + (src0-48))*32);
    const f16* c1p = (src1<48) ? (rgbc + ((size_t)ray*SC + src1)*32)
                               : (rgbf + ((size_t)ray*SF + (src1-48))*32);
    const uint4* A4 = reinterpret_cast<const uint4*>(c0p);
    const uint4* B4 = reinterpret_cast<const uint4*>(c1p);
    uint4 A[4], B[4];
    #pragma unroll
    for (int u=0;u<4;u++){ A[u]=A4[u]; B[u]=B4[u]; }
    f32x4 cacc[8];
    #pragma unroll
    for (int u=0;u<4;u++){
      unsigned int aw[4] = {A[u].x,A[u].y,A[u].z,A[u].w};
      unsigned int bw[4] = {B[u].x,B[u].y,B[u].z,B[u].w};
      #pragma unroll
      for (int w=0;w<4;w++){
        f16x2 ha = __builtin_bit_cast(f16x2, aw[w]);
        f16x2 hb = __builtin_bit_cast(f16x2, bw[w]);
        int qq = 2*u + (w>>1);
        int e  = (w&1)*2;
        cacc[qq][e+0] = fmaf(coef0,(float)ha[0], coef1*(float)hb[0]);
        cacc[qq][e+1] = fmaf(coef0,(float)ha[1], coef1*(float)hb[1]);
      }
    }
    int row = L_PT + lane*36;
    #pragma unroll
    for (int qq=0;qq<8;qq++)
      *reinterpret_cast<f32x4*>(&Sf[row + 4*qq]) = cacc[qq];
  }

  // depth / wsum butterfly
  #pragma unroll
  for (int off=1; off<64; off<<=1){
    dp += __shfl_xor(dp, off);
    wp += __shfl_xor(wp, off);
  }

  // rgb reduction: col = lane&31, two groups over rows
  int col = lane & 31, g = lane >> 5;
  float racc = 0.f;
  #pragma unroll
  for (int t=0;t<24;t++)
    racc += Sf[L_PT + (g*24+t)*36 + col];
  racc += __shfl_xor(racc, 32);
  if (g == 0) out[(size_t)ray*32 + col] = 2.0f*racc - 1.0f;
  if (lane == 0){
    out[OFF_DEPTH+ray] = dp;
    out[OFF_WSUM+ray]  = wp;
  }
}

extern "C" void kernel_launch(void* const* d_in, const int* in_sizes, int n_in,
                              void* d_out, int out_size, void* d_ws, size_t ws_size,
                              hipStream_t stream){
  const float* planes = (const float*)d_in[0];
  const float* orig   = (const float*)d_in[1];
  const float* dirs   = (const float*)d_in[2];
  const float* w1     = (const float*)d_in[3];
  const float* b1     = (const float*)d_in[4];
  const float* w2     = (const float*)d_in[5];
  const float* b2     = (const float*)d_in[6];
  float* out = (float*)d_out;
  char*  ws  = (char*)d_ws;

  f16*   pT    = (f16*)(ws + PT_B);
  f16*   rgbc  = (f16*)(ws + RGBC_B);
  f16*   rgbf  = (f16*)(ws + RGBF_B);
  float* sigf  = (float*)(ws + SIGF_B);
  float* tfine = (float*)(ws + TFINE_B);
  f16*   w1A   = (f16*)(ws + W1A_B);
  float* b1F   = (float*)(ws + B1F_B);
  f16*   w2A   = (f16*)(ws + W2A_B);
  float* b2F   = (float*)(ws + B2F_B);

  k_transpose<<<dim3(NB*3*HPX*HPX/256), dim3(256), 0, stream>>>(planes, pT);
  k_prep<<<dim3(1), dim3(256), 0, stream>>>(w1, b1, w2, b2, w1A, b1F, w2A, b2F);
  k_model<true><<<dim3(NRAY*SC/256), dim3(256), 0, stream>>>(
      pT, orig, dirs, (const uint4*)w1A, (const f32x4*)b1F, (const uint4*)w2A,
      (const f32x4*)b2F, (const float*)nullptr, rgbc, out + OFF_SDF);
  k_importance<<<dim3(NRAY/128), dim3(128), 0, stream>>>(out + OFF_SDF, tfine);
  k_model<false><<<dim3(NRAY*SF/256), dim3(256), 0, stream>>>(
      pT, orig, dirs, (const uint4*)w1A, (const f32x4*)b1F, (const uint4*)w2A,
      (const f32x4*)b2F, tfine, rgbf, sigf);
  k_final<<<dim3(NRAY/4), dim3(256), 0, stream>>>(
      out + OFF_SDF, rgbc, sigf, rgbf, tfine, out);
}

// Round 5
// 121.100 us; speedup vs baseline: 4.1431x; 1.1561x over previous
//
#include <hip/hip_runtime.h>
#include <cstddef>

#define NB 2
#define RPB 4096
#define NRAY (NB*RPB)          // 8192
#define SC 48
#define SF 48
#define CP 32
#define HPX 256
#define HID 64
#define NOUT 33

#define DTC (1.05f/47.0f)
#define TC0 (2.25f + 0.5f*(1.05f/47.0f))

// d_out layout (floats)
#define OFF_DEPTH (NRAY*32)            // 262144
#define OFF_WSUM  (OFF_DEPTH + NRAY)   // 270336
#define OFF_SDF   (OFF_WSUM + NRAY)    // 278528

// ws layout (BYTES)
#define PT_B     ((size_t)0)                    // planesT f16
#define RGBC_B   ((size_t)25165824)             // rgb coarse f16: 8192*48*32
#define RGBF_B   ((size_t)50331648)             // rgb fine  f16
#define SIGF_B   ((size_t)75497472)             // sigma fine f32
#define TFINE_B  ((size_t)77070336)             // fine depths f32
#define W1A_B    ((size_t)78643200)
#define B1F_B    ((size_t)78647296)
#define W2A_B    ((size_t)78651392)
#define B2F_B    ((size_t)78657536)

#define PL_BYTES ((size_t)HPX*HPX*CP*2)         // 4,194,304 bytes per (b,pl)

typedef _Float16 f16;
typedef _Float16 f16x2 __attribute__((ext_vector_type(2)));
typedef _Float16 f16x8 __attribute__((ext_vector_type(8)));
typedef float    f32x4 __attribute__((ext_vector_type(4)));

#define LOG2E 1.44269504f
#define LN2   0.69314718f
static __device__ __forceinline__ float fast_exp(float x){
  return __builtin_amdgcn_exp2f(x*LOG2E);
}
static __device__ __forceinline__ float softplus_f(float x){
  float e = __builtin_amdgcn_exp2f(-fabsf(x)*LOG2E);
  float l = __builtin_amdgcn_logf(1.0f + e)*LN2;
  return fmaxf(x, 0.0f) + l;
}
static __device__ __forceinline__ float fast_sigmoid_scaled(float a){
  float e = __builtin_amdgcn_exp2f(-a*LOG2E);
  return __builtin_amdgcn_rcpf(1.0f + e)*1.002f - 0.001f;
}
static __device__ __forceinline__ unsigned pack2(float a, float b){
  f16x2 h = { (f16)a, (f16)b };
  return __builtin_bit_cast(unsigned int, h);
}

// planes (b,pl,c,y,x) f32 -> planesT (b,pl,y,x,c) f16
__global__ __launch_bounds__(256) void k_transpose(const float* __restrict__ src,
                                                   f16* __restrict__ dst){
  int idx = blockIdx.x*256 + threadIdx.x;
  int xy = idx & (HPX*HPX-1);
  int bp = idx >> 16;
  const float* s = src + (size_t)bp*CP*HPX*HPX + xy;
  unsigned int w[16];
  #pragma unroll
  for (int c=0;c<CP;c+=2){
    w[c>>1] = pack2(s[(size_t)c*HPX*HPX], s[(size_t)(c+1)*HPX*HPX]);
  }
  uint4* d4 = reinterpret_cast<uint4*>(dst + (size_t)idx*CP);
  d4[0] = make_uint4(w[0],w[1],w[2],w[3]);
  d4[1] = make_uint4(w[4],w[5],w[6],w[7]);
  d4[2] = make_uint4(w[8],w[9],w[10],w[11]);
  d4[3] = make_uint4(w[12],w[13],w[14],w[15]);
}

// MFMA fragment prep
__global__ __launch_bounds__(256) void k_prep(const float* __restrict__ w1,
                                              const float* __restrict__ b1,
                                              const float* __restrict__ w2,
                                              const float* __restrict__ b2,
                                              f16* __restrict__ w1A,
                                              float* __restrict__ b1F,
                                              f16* __restrict__ w2A,
                                              float* __restrict__ b2F){
  int tid = threadIdx.x;
  {
    int m = tid>>6, lane = tid&63, q = lane>>4, r16 = lane&15;
    #pragma unroll
    for (int j=0;j<8;j++){
      int c = q*8+j, i = m*16+r16;
      w1A[(m*64+lane)*8+j] = (f16)(w1[c*HID+i]*(1.0f/3.0f));
    }
    #pragma unroll
    for (int r=0;r<4;r++) b1F[(m*64+lane)*4+r] = b1[m*16+q*4+r];
  }
  for (int idx=tid; idx<384; idx+=256){
    int f = idx>>6, lane = idx&63, q = lane>>4, r16 = lane&15;
    int kc = f/3, m2 = f - kc*3;
    int row = m2*16+r16;
    int col = (row<32)? (row+1) : ((row==32)? 0 : -1);
    #pragma unroll
    for (int j=0;j<8;j++){
      int k = kc*32+q*8+j;
      w2A[(f*64+lane)*8+j] = (col>=0)? (f16)w2[k*NOUT+col] : (f16)0.0f;
    }
  }
  if (tid<192){
    int m2 = tid>>6, lane = tid&63, q = lane>>4;
    #pragma unroll
    for (int r=0;r<4;r++){
      int row = m2*16+q*4+r;
      float v = (row<32)? b2[row+1] : ((row==32)? b2[0] : 0.0f);
      b2F[(m2*64+lane)*4+r] = v;
    }
  }
}

// records: per point, per plane: [w00x2,w01x2,w10x2,w11x2, coords, pad*3] = 8 words
// record base = point*24 + pl*8 words; h buffer reuses words [0..1152)
template<bool COARSE>
__global__ __launch_bounds__(256, 4) void k_model(
    const f16* __restrict__ pT,
    const float* __restrict__ orig,
    const float* __restrict__ dirs,
    const uint4* __restrict__ w1A,
    const f32x4* __restrict__ b1F,
    const uint4* __restrict__ w2A,
    const f32x4* __restrict__ b2F,
    const float* __restrict__ tfine,
    f16* __restrict__ rgb_out,
    float* __restrict__ sig_out)
{
  __shared__ unsigned int lds[4][1536];   // 6144 B per wave, wave-private
  int tid = threadIdx.x;
  int lane = tid & 63;
  int wv = tid >> 6;
  int q = lane >> 4;
  int c16 = lane & 15;
  unsigned int* fb = &lds[wv][0];

  // ---- phase 1: per-lane records (coords + masked corner weights) ----
  int p = blockIdx.x*256 + tid;
  {
    int ray = p / 48;
    int kk = p - ray*48;
    float t = COARSE ? (TC0 + (float)kk*DTC) : tfine[p];
    float ox = orig[ray*3+0], oy = orig[ray*3+1], oz = orig[ray*3+2];
    float dx = dirs[ray*3+0], dy = dirs[ray*3+1], dz = dirs[ray*3+2];
    float cx = fmaf(t,dx,ox), cy = fmaf(t,dy,oy), cz = fmaf(t,dz,oz);

    #pragma unroll
    for (int pl=0; pl<3; pl++){
      float u = (pl==2)? cz : cx;
      float v = (pl==0)? cy : (pl==1 ? cz : cx);
      float x = ((u+1.0f)*256.0f - 1.0f)*0.5f;
      float y = ((v+1.0f)*256.0f - 1.0f)*0.5f;
      float xf = floorf(x), yf = floorf(y);
      float wx = x-xf, wy = y-yf;
      int ix = (int)xf, iy = (int)yf;
      int x0 = min(max(ix,0),HPX-1),   x1 = min(max(ix+1,0),HPX-1);
      int y0 = min(max(iy,0),HPX-1),   y1 = min(max(iy+1,0),HPX-1);
      float vx0 = ((unsigned)ix    < (unsigned)HPX) ? 1.f : 0.f;
      float vx1 = ((unsigned)(ix+1)< (unsigned)HPX) ? 1.f : 0.f;
      float vy0 = ((unsigned)iy    < (unsigned)HPX) ? 1.f : 0.f;
      float vy1 = ((unsigned)(iy+1)< (unsigned)HPX) ? 1.f : 0.f;
      float w00 = (1.f-wx)*(1.f-wy)*vx0*vy0;
      float w01 = wx*(1.f-wy)*vx1*vy0;
      float w10 = (1.f-wx)*wy*vx0*vy1;
      float w11 = wx*wy*vx1*vy1;
      unsigned coords = (unsigned)x0 | ((unsigned)x1<<8) | ((unsigned)y0<<16) | ((unsigned)y1<<24);
      int rb = lane*24 + pl*8;
      uint4 wp = make_uint4(pack2(w00,w00), pack2(w01,w01), pack2(w10,w10), pack2(w11,w11));
      *reinterpret_cast<uint4*>(&fb[rb]) = wp;
      fb[rb+4] = coords;
    }
  }

  // ---- phase 2: cooperative gather; lane(q,c16) holds channels 8q..8q+7 of
  //      points {s*16+c16} -> directly the GEMM1 B fragments ----
  int bb = blockIdx.x / 768;   // batch index, scalar
  const char* pb0 = (const char*)pT + (size_t)(bb*3)*PL_BYTES;
  f16x2 fs[4][4];
  #pragma unroll
  for (int s=0;s<4;s++)
    #pragma unroll
    for (int j=0;j<4;j++) fs[s][j] = (f16x2){(f16)0.0f,(f16)0.0f};

  int qoff = q*16;
  #pragma unroll
  for (int s=0;s<4;s++){
    #pragma unroll
    for (int pl=0; pl<3; pl++){
      int rb = (s*16+c16)*24 + pl*8;
      uint4 w4 = *reinterpret_cast<const uint4*>(&fb[rb]);
      unsigned crd = fb[rb+4];
      const char* bp = pb0 + (size_t)pl*PL_BYTES;
      int x0 = crd & 255, x1 = (crd>>8) & 255;
      int y0 = (crd>>16) & 255, y1 = crd>>24;
      unsigned wws[4] = {w4.x, w4.y, w4.z, w4.w};
      int offs[4] = { (y0<<14)+(x0<<6)+qoff, (y0<<14)+(x1<<6)+qoff,
                      (y1<<14)+(x0<<6)+qoff, (y1<<14)+(x1<<6)+qoff };
      #pragma unroll
      for (int c=0;c<4;c++){
        uint4 d = *reinterpret_cast<const uint4*>(bp + offs[c]);
        f16x2 wv2 = __builtin_bit_cast(f16x2, wws[c]);
        fs[s][0] += __builtin_bit_cast(f16x2, d.x) * wv2;
        fs[s][1] += __builtin_bit_cast(f16x2, d.y) * wv2;
        fs[s][2] += __builtin_bit_cast(f16x2, d.z) * wv2;
        fs[s][3] += __builtin_bit_cast(f16x2, d.w) * wv2;
      }
    }
  }

  f16x8 bfr[4];
  #pragma unroll
  for (int n=0;n<4;n++){
    uint4 u = make_uint4(__builtin_bit_cast(unsigned, fs[n][0]),
                         __builtin_bit_cast(unsigned, fs[n][1]),
                         __builtin_bit_cast(unsigned, fs[n][2]),
                         __builtin_bit_cast(unsigned, fs[n][3]));
    bfr[n] = __builtin_bit_cast(f16x8, u);
  }

  // ---- phases 3-4: GEMM1 (k-half at a time) -> softplus -> h LDS -> GEMM2 ----
  f32x4 acc2[3][4];
  #pragma unroll
  for (int m2=0;m2<3;m2++){
    f32x4 binit = b2F[m2*64+lane];
    #pragma unroll
    for (int n=0;n<4;n++) acc2[m2][n] = binit;
  }

  #pragma unroll
  for (int half=0; half<2; half++){
    f16x8 a0 = __builtin_bit_cast(f16x8, w1A[(2*half+0)*64+lane]);
    f16x8 a1 = __builtin_bit_cast(f16x8, w1A[(2*half+1)*64+lane]);
    f32x4 i0 = b1F[(2*half+0)*64+lane];
    f32x4 i1 = b1F[(2*half+1)*64+lane];
    f32x4 accA[4], accB[4];
    #pragma unroll
    for (int n=0;n<4;n++){
      accA[n] = __builtin_amdgcn_mfma_f32_16x16x32_f16(a0, bfr[n], i0, 0,0,0);
      accB[n] = __builtin_amdgcn_mfma_f32_16x16x32_f16(a1, bfr[n], i1, 0,0,0);
    }
    // write h (this k-half) : point P row stride 18 words
    #pragma unroll
    for (int n=0;n<4;n++){
      int P = n*16 + c16;
      uint2 vA, vB;
      vA.x = pack2(softplus_f(accA[n][0]), softplus_f(accA[n][1]));
      vA.y = pack2(softplus_f(accA[n][2]), softplus_f(accA[n][3]));
      vB.x = pack2(softplus_f(accB[n][0]), softplus_f(accB[n][1]));
      vB.y = pack2(softplus_f(accB[n][2]), softplus_f(accB[n][3]));
      *reinterpret_cast<uint2*>(&fb[P*18 + 0 + q*2]) = vA;
      *reinterpret_cast<uint2*>(&fb[P*18 + 8 + q*2]) = vB;
    }
    // read B-frags for this k-half, GEMM2 accumulate
    f16x8 b2f[4];
    #pragma unroll
    for (int n=0;n<4;n++){
      int P = n*16 + c16;
      uint4 u = *reinterpret_cast<const uint4*>(&fb[P*18 + q*4]);
      b2f[n] = __builtin_bit_cast(f16x8, u);
    }
    #pragma unroll
    for (int m2=0;m2<3;m2++){
      f16x8 a = __builtin_bit_cast(f16x8, w2A[(half*3+m2)*64+lane]);
      #pragma unroll
      for (int n=0;n<4;n++)
        acc2[m2][n] = __builtin_amdgcn_mfma_f32_16x16x32_f16(a, b2f[n], acc2[m2][n], 0,0,0);
    }
  }

  // ---- phase 5: outputs. rows 0..31 = rgb channels, row 32 = sigma ----
  int pbase = blockIdx.x*256 + wv*64;
  #pragma unroll
  for (int n=0;n<4;n++){
    int P = pbase + n*16 + c16;
    #pragma unroll
    for (int m2=0;m2<2;m2++){
      f32x4 v = acc2[m2][n];
      int ch = m2*16 + q*4;
      uint2 v2;
      v2.x = pack2(fast_sigmoid_scaled(v[0]), fast_sigmoid_scaled(v[1]));
      v2.y = pack2(fast_sigmoid_scaled(v[2]), fast_sigmoid_scaled(v[3]));
      *reinterpret_cast<uint2*>(rgb_out + (size_t)P*32 + ch) = v2;
    }
    if (q==0) sig_out[P] = acc2[2][n][0];
  }
}

// coarse march -> importance CDF resample -> fine depths
__global__ __launch_bounds__(64) void k_importance(const float* __restrict__ sg_all,
                                                   float* __restrict__ tfine){
  __shared__ float sC[64][46];
  int tid = threadIdx.x;
  int ray = blockIdx.x*64 + tid;
  const float* sg = sg_all + (size_t)ray*SC;
  float T = 1.0f;
  float sum = 0.0f;
  float s_prev = sg[0];
  float wm1 = 0.f, wm2 = 0.f;
  for (int k=0;k<47;k++){
    float s_next = sg[k+1];
    float dm = softplus_f(0.5f*(s_prev+s_next)-1.0f);
    float alpha = 1.0f - fast_exp(-dm*DTC);
    float wk = alpha*T;
    T *= (1.0f - alpha + 1e-10f);
    s_prev = s_next;
    if (k>=2){
      float qv = 0.5f*(fmaxf(wm2,wm1)+fmaxf(wm1,wk)) + 0.01f;
      sC[tid][k-1] = qv;
      sum += qv;
    }
    wm2 = wm1; wm1 = wk;
  }
  sC[tid][0] = 0.0f;
  float run = 0.0f;
  float rsum = 1.0f/sum;
  for (int i=1;i<=45;i++){
    run += sC[tid][i]*rsum;
    sC[tid][i] = run;
  }
  float* tf = tfine + (size_t)ray*SF;
  int idx = 1;
  for (int j=0;j<48;j++){
    float u = (float)j/47.0f;
    while (idx<46 && sC[tid][idx] <= u) idx++;
    int below = idx-1;
    int above = (idx<46) ? idx : 45;
    float cb = sC[tid][below];
    float ca = sC[tid][above];
    float bb = TC0 + ((float)below+0.5f)*DTC;
    float ba = TC0 + ((float)above+0.5f)*DTC;
    float denom = ca - cb;
    if (denom < 1e-5f) denom = 1.0f;
    tf[j] = bb + (u-cb)/denom*(ba-bb);
  }
}

// wave-per-ray parallel merge + scan + march
#define L_DF  0
#define L_SC  48
#define L_SF  96
#define L_DM  144
#define L_SM  240
#define L_SRC 336
#define L_PT  432
#define SLAB  2160

__global__ __launch_bounds__(256) void k_final(
    const float* __restrict__ sigc, const f16* __restrict__ rgbc,
    const float* __restrict__ sigf, const f16* __restrict__ rgbf,
    const float* __restrict__ tfine, float* __restrict__ out)
{
  __shared__ unsigned int slab[4][SLAB];
  int lane = threadIdx.x & 63;
  int wv = threadIdx.x >> 6;
  int ray = blockIdx.x*4 + wv;
  unsigned int* S = &slab[wv][0];
  float* Sf = (float*)S;

  if (lane < 48){
    Sf[L_DF+lane] = tfine[(size_t)ray*SF + lane];
    Sf[L_SC+lane] = sigc[(size_t)ray*SC + lane];
    Sf[L_SF+lane] = sigf[(size_t)ray*SF + lane];
  }

  if (lane < 48){
    float dcv = TC0 + (float)lane*DTC;
    int pos = 0;
    #pragma unroll
    for (int stp=32; stp>=1; stp>>=1){
      int np = pos + stp;
      if (np <= 48 && Sf[L_DF+np-1] < dcv) pos = np;
    }
    int rank_c = lane + pos;
    Sf[L_DM+rank_c] = dcv;
    Sf[L_SM+rank_c] = Sf[L_SC+lane];
    S [L_SRC+rank_c] = lane;
    float x = Sf[L_DF+lane];
    int cnt = (int)(floorf((x - TC0)*(1.0f/DTC)) + 1.0f);
    cnt = min(max(cnt,0),48);
    while (cnt < 48 && (TC0 + (float)cnt*DTC) <= x) cnt++;
    while (cnt > 0 && (TC0 + (float)(cnt-1)*DTC) > x) cnt--;
    int rank_f = lane + cnt;
    Sf[L_DM+rank_f] = x;
    Sf[L_SM+rank_f] = Sf[L_SF+lane];
    S [L_SRC+rank_f] = 48 + lane;
  }

  int s0 = 2*lane, s1 = 2*lane+1;
  float alpha0=0.f, alpha1=0.f, g0=1.f, g1=1.f;
  float d0=0.f, d1=0.f, d2=0.f;
  if (lane < 48){
    int s2i = min(s1+1, 95);
    d0 = Sf[L_DM+s0]; d1 = Sf[L_DM+s1]; d2 = Sf[L_DM+s2i];
    float m0 = Sf[L_SM+s0], m1 = Sf[L_SM+s1], m2 = Sf[L_SM+s2i];
    {
      float dm = softplus_f(0.5f*(m0+m1)-1.0f);
      alpha0 = 1.0f - fast_exp(-dm*(d1-d0));
      g0 = 1.0f - alpha0 + 1e-10f;
    }
    if (lane < 47){
      float dm = softplus_f(0.5f*(m1+m2)-1.0f);
      alpha1 = 1.0f - fast_exp(-dm*(d2-d1));
      g1 = 1.0f - alpha1 + 1e-10f;
    }
  }
  float ip = g0*g1;
  #pragma unroll
  for (int off=1; off<64; off<<=1){
    float v = __shfl_up(ip, off);
    if (lane >= off) ip *= v;
  }
  float E = __shfl_up(ip, 1);
  if (lane == 0) E = 1.0f;
  float w0 = alpha0*E;
  float w1 = alpha1*E*g0;
  float wprev = __shfl_up(w1, 1);
  if (lane == 0) wprev = 0.0f;
  float coef0 = 0.5f*(wprev + w0);
  float coef1 = 0.5f*(w0 + w1);
  float dp = (lane<48) ? (w0*0.5f*(d0+d1) + w1*0.5f*(d1+d2)) : 0.f;
  float wp = w0 + w1;

  if (lane < 48){
    int src0 = (int)S[L_SRC+s0], src1 = (int)S[L_SRC+s1];
    const f16* c0p = (src0<48) ? (rgbc + ((size_t)ray*SC + src0)*32)
                               : (rgbf + ((size_t)ray*SF + (src0-48))*32);
    const f16* c1p = (src1<48) ? (rgbc + ((size_t)ray*SC + src1)*32)
                               : (rgbf + ((size_t)ray*SF + (src1-48))*32);
    const uint4* A4 = reinterpret_cast<const uint4*>(c0p);
    const uint4* B4 = reinterpret_cast<const uint4*>(c1p);
    uint4 A[4], B[4];
    #pragma unroll
    for (int u=0;u<4;u++){ A[u]=A4[u]; B[u]=B4[u]; }
    f32x4 cacc[8];
    #pragma unroll
    for (int u=0;u<4;u++){
      unsigned int aw[4] = {A[u].x,A[u].y,A[u].z,A[u].w};
      unsigned int bw[4] = {B[u].x,B[u].y,B[u].z,B[u].w};
      #pragma unroll
      for (int w=0;w<4;w++){
        f16x2 ha = __builtin_bit_cast(f16x2, aw[w]);
        f16x2 hb = __builtin_bit_cast(f16x2, bw[w]);
        int qq = 2*u + (w>>1);
        int e  = (w&1)*2;
        cacc[qq][e+0] = fmaf(coef0,(float)ha[0], coef1*(float)hb[0]);
        cacc[qq][e+1] = fmaf(coef0,(float)ha[1], coef1*(float)hb[1]);
      }
    }
    int row = L_PT + lane*36;
    #pragma unroll
    for (int qq=0;qq<8;qq++)
      *reinterpret_cast<f32x4*>(&Sf[row + 4*qq]) = cacc[qq];
  }

  #pragma unroll
  for (int off=1; off<64; off<<=1){
    dp += __shfl_xor(dp, off);
    wp += __shfl_xor(wp, off);
  }

  int col = lane & 31, g = lane >> 5;
  float racc = 0.f;
  #pragma unroll
  for (int t=0;t<24;t++)
    racc += Sf[L_PT + (g*24+t)*36 + col];
  racc += __shfl_xor(racc, 32);
  if (g == 0) out[(size_t)ray*32 + col] = 2.0f*racc - 1.0f;
  if (lane == 0){
    out[OFF_DEPTH+ray] = dp;
    out[OFF_WSUM+ray]  = wp;
  }
}

extern "C" void kernel_launch(void* const* d_in, const int* in_sizes, int n_in,
                              void* d_out, int out_size, void* d_ws, size_t ws_size,
                              hipStream_t stream){
  const float* planes = (const float*)d_in[0];
  const float* orig   = (const float*)d_in[1];
  const float* dirs   = (const float*)d_in[2];
  const float* w1     = (const float*)d_in[3];
  const float* b1     = (const float*)d_in[4];
  const float* w2     = (const float*)d_in[5];
  const float* b2     = (const float*)d_in[6];
  float* out = (float*)d_out;
  char*  ws  = (char*)d_ws;

  f16*   pT    = (f16*)(ws + PT_B);
  f16*   rgbc  = (f16*)(ws + RGBC_B);
  f16*   rgbf  = (f16*)(ws + RGBF_B);
  float* sigf  = (float*)(ws + SIGF_B);
  float* tfine = (float*)(ws + TFINE_B);
  f16*   w1A   = (f16*)(ws + W1A_B);
  float* b1F   = (float*)(ws + B1F_B);
  f16*   w2A   = (f16*)(ws + W2A_B);
  float* b2F   = (float*)(ws + B2F_B);

  k_transpose<<<dim3(NB*3*HPX*HPX/256), dim3(256), 0, stream>>>(planes, pT);
  k_prep<<<dim3(1), dim3(256), 0, stream>>>(w1, b1, w2, b2, w1A, b1F, w2A, b2F);
  k_model<true><<<dim3(NRAY*SC/256), dim3(256), 0, stream>>>(
      pT, orig, dirs, (const uint4*)w1A, (const f32x4*)b1F, (const uint4*)w2A,
      (const f32x4*)b2F, (const float*)nullptr, rgbc, out + OFF_SDF);
  k_importance<<<dim3(NRAY/64), dim3(64), 0, stream>>>(out + OFF_SDF, tfine);
  k_model<false><<<dim3(NRAY*SF/256), dim3(256), 0, stream>>>(
      pT, orig, dirs, (const uint4*)w1A, (const f32x4*)b1F, (const uint4*)w2A,
      (const f32x4*)b2F, tfine, rgbf, sigf);
  k_final<<<dim3(NRAY/4), dim3(256), 0, stream>>>(
      out + OFF_SDF, rgbc, sigf, rgbf, tfine, out);
}

// Round 6
// 120.696 us; speedup vs baseline: 4.1569x; 1.0033x over previous
//
#include <hip/hip_runtime.h>
#include <cstddef>

#define NB 2
#define RPB 4096
#define NRAY (NB*RPB)          // 8192
#define SC 48
#define SF 48
#define CP 32
#define HPX 256
#define HID 64
#define NOUT 33

#define DTC (1.05f/47.0f)
#define TC0 (2.25f + 0.5f*(1.05f/47.0f))

// d_out layout (floats)
#define OFF_DEPTH (NRAY*32)            // 262144
#define OFF_WSUM  (OFF_DEPTH + NRAY)   // 270336
#define OFF_SDF   (OFF_WSUM + NRAY)    // 278528

// ws layout (BYTES)
#define PT_B     ((size_t)0)                    // planesT f16
#define RGBC_B   ((size_t)25165824)             // rgb coarse f16: 8192*48*32
#define RGBF_B   ((size_t)50331648)             // rgb fine  f16
#define SIGF_B   ((size_t)75497472)             // sigma fine f32
#define TFINE_B  ((size_t)77070336)             // fine depths f32
#define W1A_B    ((size_t)78643200)
#define B1F_B    ((size_t)78647296)
#define W2A_B    ((size_t)78651392)
#define B2F_B    ((size_t)78657536)

#define PL_BYTES ((size_t)HPX*HPX*CP*2)         // 4,194,304 bytes per (b,pl)

typedef _Float16 f16;
typedef _Float16 f16x2 __attribute__((ext_vector_type(2)));
typedef _Float16 f16x8 __attribute__((ext_vector_type(8)));
typedef float    f32x4 __attribute__((ext_vector_type(4)));

#define LOG2E 1.44269504f
#define LN2   0.69314718f
static __device__ __forceinline__ float fast_exp(float x){
  return __builtin_amdgcn_exp2f(x*LOG2E);
}
static __device__ __forceinline__ float softplus_f(float x){
  float e = __builtin_amdgcn_exp2f(-fabsf(x)*LOG2E);
  float l = __builtin_amdgcn_logf(1.0f + e)*LN2;
  return fmaxf(x, 0.0f) + l;
}
static __device__ __forceinline__ float fast_sigmoid_scaled(float a){
  float e = __builtin_amdgcn_exp2f(-a*LOG2E);
  return __builtin_amdgcn_rcpf(1.0f + e)*1.002f - 0.001f;
}
static __device__ __forceinline__ unsigned pack2(float a, float b){
  f16x2 h = { (f16)a, (f16)b };
  return __builtin_bit_cast(unsigned int, h);
}

// planes (b,pl,c,y,x) f32 -> planesT (b,pl,y,x,c) f16
__global__ __launch_bounds__(256) void k_transpose(const float* __restrict__ src,
                                                   f16* __restrict__ dst){
  int idx = blockIdx.x*256 + threadIdx.x;
  int xy = idx & (HPX*HPX-1);
  int bp = idx >> 16;
  const float* s = src + (size_t)bp*CP*HPX*HPX + xy;
  unsigned int w[16];
  #pragma unroll
  for (int c=0;c<CP;c+=2){
    w[c>>1] = pack2(s[(size_t)c*HPX*HPX], s[(size_t)(c+1)*HPX*HPX]);
  }
  uint4* d4 = reinterpret_cast<uint4*>(dst + (size_t)idx*CP);
  d4[0] = make_uint4(w[0],w[1],w[2],w[3]);
  d4[1] = make_uint4(w[4],w[5],w[6],w[7]);
  d4[2] = make_uint4(w[8],w[9],w[10],w[11]);
  d4[3] = make_uint4(w[12],w[13],w[14],w[15]);
}

// MFMA fragment prep
__global__ __launch_bounds__(256) void k_prep(const float* __restrict__ w1,
                                              const float* __restrict__ b1,
                                              const float* __restrict__ w2,
                                              const float* __restrict__ b2,
                                              f16* __restrict__ w1A,
                                              float* __restrict__ b1F,
                                              f16* __restrict__ w2A,
                                              float* __restrict__ b2F){
  int tid = threadIdx.x;
  {
    int m = tid>>6, lane = tid&63, q = lane>>4, r16 = lane&15;
    #pragma unroll
    for (int j=0;j<8;j++){
      int c = q*8+j, i = m*16+r16;
      w1A[(m*64+lane)*8+j] = (f16)(w1[c*HID+i]*(1.0f/3.0f));
    }
    #pragma unroll
    for (int r=0;r<4;r++) b1F[(m*64+lane)*4+r] = b1[m*16+q*4+r];
  }
  for (int idx=tid; idx<384; idx+=256){
    int f = idx>>6, lane = idx&63, q = lane>>4, r16 = lane&15;
    int kc = f/3, m2 = f - kc*3;
    int row = m2*16+r16;
    int col = (row<32)? (row+1) : ((row==32)? 0 : -1);
    #pragma unroll
    for (int j=0;j<8;j++){
      int k = kc*32+q*8+j;
      w2A[(f*64+lane)*8+j] = (col>=0)? (f16)w2[k*NOUT+col] : (f16)0.0f;
    }
  }
  if (tid<192){
    int m2 = tid>>6, lane = tid&63, q = lane>>4;
    #pragma unroll
    for (int r=0;r<4;r++){
      int row = m2*16+q*4+r;
      float v = (row<32)? b2[row+1] : ((row==32)? b2[0] : 0.0f);
      b2F[(m2*64+lane)*4+r] = v;
    }
  }
}

// Records live in VGPRs (5 words per plane: 4 packed weights + coords),
// broadcast to consumer lanes via __shfl (ds_bpermute). LDS holds only h.
template<bool COARSE>
__global__ __launch_bounds__(256, 4) void k_model(
    const f16* __restrict__ pT,
    const float* __restrict__ orig,
    const float* __restrict__ dirs,
    const uint4* __restrict__ w1A,
    const f32x4* __restrict__ b1F,
    const uint4* __restrict__ w2A,
    const f32x4* __restrict__ b2F,
    const float* __restrict__ tfine,
    f16* __restrict__ rgb_out,
    float* __restrict__ sig_out)
{
  __shared__ unsigned int lds[4][1152];   // h only: 4608 B per wave, wave-private
  int tid = threadIdx.x;
  int lane = tid & 63;
  int wv = tid >> 6;
  int q = lane >> 4;
  int c16 = lane & 15;
  unsigned int* fb = &lds[wv][0];

  // ---- phase 1: per-lane records for OWN point, kept in registers ----
  unsigned wrec[3][4];
  unsigned crec[3];
  int p = blockIdx.x*256 + tid;
  {
    int ray = p / 48;
    int kk = p - ray*48;
    float t = COARSE ? (TC0 + (float)kk*DTC) : tfine[p];
    float ox = orig[ray*3+0], oy = orig[ray*3+1], oz = orig[ray*3+2];
    float dx = dirs[ray*3+0], dy = dirs[ray*3+1], dz = dirs[ray*3+2];
    float cx = fmaf(t,dx,ox), cy = fmaf(t,dy,oy), cz = fmaf(t,dz,oz);

    #pragma unroll
    for (int pl=0; pl<3; pl++){
      float u = (pl==2)? cz : cx;
      float v = (pl==0)? cy : (pl==1 ? cz : cx);
      float x = ((u+1.0f)*256.0f - 1.0f)*0.5f;
      float y = ((v+1.0f)*256.0f - 1.0f)*0.5f;
      float xf = floorf(x), yf = floorf(y);
      float wx = x-xf, wy = y-yf;
      int ix = (int)xf, iy = (int)yf;
      int x0 = min(max(ix,0),HPX-1),   x1 = min(max(ix+1,0),HPX-1);
      int y0 = min(max(iy,0),HPX-1),   y1 = min(max(iy+1,0),HPX-1);
      float vx0 = ((unsigned)ix    < (unsigned)HPX) ? 1.f : 0.f;
      float vx1 = ((unsigned)(ix+1)< (unsigned)HPX) ? 1.f : 0.f;
      float vy0 = ((unsigned)iy    < (unsigned)HPX) ? 1.f : 0.f;
      float vy1 = ((unsigned)(iy+1)< (unsigned)HPX) ? 1.f : 0.f;
      float w00 = (1.f-wx)*(1.f-wy)*vx0*vy0;
      float w01 = wx*(1.f-wy)*vx1*vy0;
      float w10 = (1.f-wx)*wy*vx0*vy1;
      float w11 = wx*wy*vx1*vy1;
      wrec[pl][0] = pack2(w00,w00);
      wrec[pl][1] = pack2(w01,w01);
      wrec[pl][2] = pack2(w10,w10);
      wrec[pl][3] = pack2(w11,w11);
      crec[pl] = (unsigned)x0 | ((unsigned)x1<<8) | ((unsigned)y0<<16) | ((unsigned)y1<<24);
    }
  }

  // ---- phase 2: cooperative gather; lane(q,c16) accumulates channels 8q..8q+7
  //      of points {s*16+c16} -> directly the GEMM1 B fragments ----
  int bb = blockIdx.x / 768;   // batch index (scalar)
  const char* pb0 = (const char*)pT + (size_t)(bb*3)*PL_BYTES;
  f16x2 fs[4][4];
  #pragma unroll
  for (int s=0;s<4;s++)
    #pragma unroll
    for (int j=0;j<4;j++) fs[s][j] = (f16x2){(f16)0.0f,(f16)0.0f};

  int qoff = q*16;
  #pragma unroll
  for (int s=0;s<4;s++){
    int srcl = s*16 + c16;
    // fetch the 3 plane-records of point srcl via cross-lane broadcast
    unsigned rw[12], rc[3];
    #pragma unroll
    for (int pl=0;pl<3;pl++){
      #pragma unroll
      for (int k=0;k<4;k++)
        rw[pl*4+k] = (unsigned)__shfl((int)wrec[pl][k], srcl);
      rc[pl] = (unsigned)__shfl((int)crec[pl], srcl);
    }
    // compute all 12 addresses
    int offs[12];
    #pragma unroll
    for (int pl=0;pl<3;pl++){
      unsigned crd = rc[pl];
      int x0 = crd & 255, x1 = (crd>>8) & 255;
      int y0 = (crd>>16) & 255, y1 = crd>>24;
      int pbase = (int)(pl*(int)PL_BYTES);
      offs[pl*4+0] = pbase + (y0<<14)+(x0<<6)+qoff;
      offs[pl*4+1] = pbase + (y0<<14)+(x1<<6)+qoff;
      offs[pl*4+2] = pbase + (y1<<14)+(x0<<6)+qoff;
      offs[pl*4+3] = pbase + (y1<<14)+(x1<<6)+qoff;
    }
    // issue all 12 loads before use
    uint4 L[12];
    #pragma unroll
    for (int j=0;j<12;j++)
      L[j] = *reinterpret_cast<const uint4*>(pb0 + offs[j]);
    // accumulate
    #pragma unroll
    for (int j=0;j<12;j++){
      f16x2 wv2 = __builtin_bit_cast(f16x2, rw[j]);
      fs[s][0] += __builtin_bit_cast(f16x2, L[j].x) * wv2;
      fs[s][1] += __builtin_bit_cast(f16x2, L[j].y) * wv2;
      fs[s][2] += __builtin_bit_cast(f16x2, L[j].z) * wv2;
      fs[s][3] += __builtin_bit_cast(f16x2, L[j].w) * wv2;
    }
  }

  f16x8 bfr[4];
  #pragma unroll
  for (int n=0;n<4;n++){
    uint4 u = make_uint4(__builtin_bit_cast(unsigned, fs[n][0]),
                         __builtin_bit_cast(unsigned, fs[n][1]),
                         __builtin_bit_cast(unsigned, fs[n][2]),
                         __builtin_bit_cast(unsigned, fs[n][3]));
    bfr[n] = __builtin_bit_cast(f16x8, u);
  }

  // ---- phases 3-4: GEMM1 (k-half) -> softplus -> h LDS -> GEMM2 ----
  f32x4 acc2[3][4];
  #pragma unroll
  for (int m2=0;m2<3;m2++){
    f32x4 binit = b2F[m2*64+lane];
    #pragma unroll
    for (int n=0;n<4;n++) acc2[m2][n] = binit;
  }

  #pragma unroll
  for (int half=0; half<2; half++){
    f16x8 a0 = __builtin_bit_cast(f16x8, w1A[(2*half+0)*64+lane]);
    f16x8 a1 = __builtin_bit_cast(f16x8, w1A[(2*half+1)*64+lane]);
    f32x4 i0 = b1F[(2*half+0)*64+lane];
    f32x4 i1 = b1F[(2*half+1)*64+lane];
    f32x4 accA[4], accB[4];
    #pragma unroll
    for (int n=0;n<4;n++){
      accA[n] = __builtin_amdgcn_mfma_f32_16x16x32_f16(a0, bfr[n], i0, 0,0,0);
      accB[n] = __builtin_amdgcn_mfma_f32_16x16x32_f16(a1, bfr[n], i1, 0,0,0);
    }
    #pragma unroll
    for (int n=0;n<4;n++){
      int P = n*16 + c16;
      uint2 vA, vB;
      vA.x = pack2(softplus_f(accA[n][0]), softplus_f(accA[n][1]));
      vA.y = pack2(softplus_f(accA[n][2]), softplus_f(accA[n][3]));
      vB.x = pack2(softplus_f(accB[n][0]), softplus_f(accB[n][1]));
      vB.y = pack2(softplus_f(accB[n][2]), softplus_f(accB[n][3]));
      *reinterpret_cast<uint2*>(&fb[P*18 + 0 + q*2]) = vA;
      *reinterpret_cast<uint2*>(&fb[P*18 + 8 + q*2]) = vB;
    }
    f16x8 b2f[4];
    #pragma unroll
    for (int n=0;n<4;n++){
      int P = n*16 + c16;
      uint4 u = *reinterpret_cast<const uint4*>(&fb[P*18 + q*4]);
      b2f[n] = __builtin_bit_cast(f16x8, u);
    }
    #pragma unroll
    for (int m2=0;m2<3;m2++){
      f16x8 a = __builtin_bit_cast(f16x8, w2A[(half*3+m2)*64+lane]);
      #pragma unroll
      for (int n=0;n<4;n++)
        acc2[m2][n] = __builtin_amdgcn_mfma_f32_16x16x32_f16(a, b2f[n], acc2[m2][n], 0,0,0);
    }
  }

  // ---- phase 5: outputs. rows 0..31 = rgb channels, row 32 = sigma ----
  int pbase = blockIdx.x*256 + wv*64;
  #pragma unroll
  for (int n=0;n<4;n++){
    int P = pbase + n*16 + c16;
    #pragma unroll
    for (int m2=0;m2<2;m2++){
      f32x4 v = acc2[m2][n];
      int ch = m2*16 + q*4;
      uint2 v2;
      v2.x = pack2(fast_sigmoid_scaled(v[0]), fast_sigmoid_scaled(v[1]));
      v2.y = pack2(fast_sigmoid_scaled(v[2]), fast_sigmoid_scaled(v[3]));
      *reinterpret_cast<uint2*>(rgb_out + (size_t)P*32 + ch) = v2;
    }
    if (q==0) sig_out[P] = acc2[2][n][0];
  }
}

// coarse march -> importance CDF resample -> fine depths
__global__ __launch_bounds__(64) void k_importance(const float* __restrict__ sg_all,
                                                   float* __restrict__ tfine){
  __shared__ float sC[64][46];
  int tid = threadIdx.x;
  int ray = blockIdx.x*64 + tid;
  const float* sg = sg_all + (size_t)ray*SC;
  float T = 1.0f;
  float sum = 0.0f;
  float s_prev = sg[0];
  float wm1 = 0.f, wm2 = 0.f;
  for (int k=0;k<47;k++){
    float s_next = sg[k+1];
    float dm = softplus_f(0.5f*(s_prev+s_next)-1.0f);
    float alpha = 1.0f - fast_exp(-dm*DTC);
    float wk = alpha*T;
    T *= (1.0f - alpha + 1e-10f);
    s_prev = s_next;
    if (k>=2){
      float qv = 0.5f*(fmaxf(wm2,wm1)+fmaxf(wm1,wk)) + 0.01f;
      sC[tid][k-1] = qv;
      sum += qv;
    }
    wm2 = wm1; wm1 = wk;
  }
  sC[tid][0] = 0.0f;
  float run = 0.0f;
  float rsum = 1.0f/sum;
  for (int i=1;i<=45;i++){
    run += sC[tid][i]*rsum;
    sC[tid][i] = run;
  }
  float* tf = tfine + (size_t)ray*SF;
  int idx = 1;
  for (int j=0;j<48;j++){
    float u = (float)j/47.0f;
    while (idx<46 && sC[tid][idx] <= u) idx++;
    int below = idx-1;
    int above = (idx<46) ? idx : 45;
    float cb = sC[tid][below];
    float ca = sC[tid][above];
    float bb = TC0 + ((float)below+0.5f)*DTC;
    float ba = TC0 + ((float)above+0.5f)*DTC;
    float denom = ca - cb;
    if (denom < 1e-5f) denom = 1.0f;
    tf[j] = bb + (u-cb)/denom*(ba-bb);
  }
}

// wave-per-ray parallel merge + scan + march
#define L_DF  0
#define L_SC  48
#define L_SF  96
#define L_DM  144
#define L_SM  240
#define L_SRC 336
#define L_PT  432
#define SLAB  2160

__global__ __launch_bounds__(256) void k_final(
    const float* __restrict__ sigc, const f16* __restrict__ rgbc,
    const float* __restrict__ sigf, const f16* __restrict__ rgbf,
    const float* __restrict__ tfine, float* __restrict__ out)
{
  __shared__ unsigned int slab[4][SLAB];
  int lane = threadIdx.x & 63;
  int wv = threadIdx.x >> 6;
  int ray = blockIdx.x*4 + wv;
  unsigned int* S = &slab[wv][0];
  float* Sf = (float*)S;

  if (lane < 48){
    Sf[L_DF+lane] = tfine[(size_t)ray*SF + lane];
    Sf[L_SC+lane] = sigc[(size_t)ray*SC + lane];
    Sf[L_SF+lane] = sigf[(size_t)ray*SF + lane];
  }

  if (lane < 48){
    float dcv = TC0 + (float)lane*DTC;
    int pos = 0;
    #pragma unroll
    for (int stp=32; stp>=1; stp>>=1){
      int np = pos + stp;
      if (np <= 48 && Sf[L_DF+np-1] < dcv) pos = np;
    }
    int rank_c = lane + pos;
    Sf[L_DM+rank_c] = dcv;
    Sf[L_SM+rank_c] = Sf[L_SC+lane];
    S [L_SRC+rank_c] = lane;
    float x = Sf[L_DF+lane];
    int cnt = (int)(floorf((x - TC0)*(1.0f/DTC)) + 1.0f);
    cnt = min(max(cnt,0),48);
    while (cnt < 48 && (TC0 + (float)cnt*DTC) <= x) cnt++;
    while (cnt > 0 && (TC0 + (float)(cnt-1)*DTC) > x) cnt--;
    int rank_f = lane + cnt;
    Sf[L_DM+rank_f] = x;
    Sf[L_SM+rank_f] = Sf[L_SF+lane];
    S [L_SRC+rank_f] = 48 + lane;
  }

  int s0 = 2*lane, s1 = 2*lane+1;
  float alpha0=0.f, alpha1=0.f, g0=1.f, g1=1.f;
  float d0=0.f, d1=0.f, d2=0.f;
  if (lane < 48){
    int s2i = min(s1+1, 95);
    d0 = Sf[L_DM+s0]; d1 = Sf[L_DM+s1]; d2 = Sf[L_DM+s2i];
    float m0 = Sf[L_SM+s0], m1 = Sf[L_SM+s1], m2 = Sf[L_SM+s2i];
    {
      float dm = softplus_f(0.5f*(m0+m1)-1.0f);
      alpha0 = 1.0f - fast_exp(-dm*(d1-d0));
      g0 = 1.0f - alpha0 + 1e-10f;
    }
    if (lane < 47){
      float dm = softplus_f(0.5f*(m1+m2)-1.0f);
      alpha1 = 1.0f - fast_exp(-dm*(d2-d1));
      g1 = 1.0f - alpha1 + 1e-10f;
    }
  }
  float ip = g0*g1;
  #pragma unroll
  for (int off=1; off<64; off<<=1){
    float v = __shfl_up(ip, off);
    if (lane >= off) ip *= v;
  }
  float E = __shfl_up(ip, 1);
  if (lane == 0) E = 1.0f;
  float w0 = alpha0*E;
  float w1 = alpha1*E*g0;
  float wprev = __shfl_up(w1, 1);
  if (lane == 0) wprev = 0.0f;
  float coef0 = 0.5f*(wprev + w0);
  float coef1 = 0.5f*(w0 + w1);
  float dp = (lane<48) ? (w0*0.5f*(d0+d1) + w1*0.5f*(d1+d2)) : 0.f;
  float wp = w0 + w1;

  if (lane < 48){
    int src0 = (int)S[L_SRC+s0], src1 = (int)S[L_SRC+s1];
    const f16* c0p = (src0<48) ? (rgbc + ((size_t)ray*SC + src0)*32)
                               : (rgbf + ((size_t)ray*SF + (src0-48))*32);
    const f16* c1p = (src1<48) ? (rgbc + ((size_t)ray*SC + src1)*32)
                               : (rgbf + ((size_t)ray*SF + (src1-48))*32);
    const uint4* A4 = reinterpret_cast<const uint4*>(c0p);
    const uint4* B4 = reinterpret_cast<const uint4*>(c1p);
    uint4 A[4], B[4];
    #pragma unroll
    for (int u=0;u<4;u++){ A[u]=A4[u]; B[u]=B4[u]; }
    f32x4 cacc[8];
    #pragma unroll
    for (int u=0;u<4;u++){
      unsigned int aw[4] = {A[u].x,A[u].y,A[u].z,A[u].w};
      unsigned int bw[4] = {B[u].x,B[u].y,B[u].z,B[u].w};
      #pragma unroll
      for (int w=0;w<4;w++){
        f16x2 ha = __builtin_bit_cast(f16x2, aw[w]);
        f16x2 hb = __builtin_bit_cast(f16x2, bw[w]);
        int qq = 2*u + (w>>1);
        int e  = (w&1)*2;
        cacc[qq][e+0] = fmaf(coef0,(float)ha[0], coef1*(float)hb[0]);
        cacc[qq][e+1] = fmaf(coef0,(float)ha[1], coef1*(float)hb[1]);
      }
    }
    int row = L_PT + lane*36;
    #pragma unroll
    for (int qq=0;qq<8;qq++)
      *reinterpret_cast<f32x4*>(&Sf[row + 4*qq]) = cacc[qq];
  }

  #pragma unroll
  for (int off=1; off<64; off<<=1){
    dp += __shfl_xor(dp, off);
    wp += __shfl_xor(wp, off);
  }

  int col = lane & 31, g = lane >> 5;
  float racc = 0.f;
  #pragma unroll
  for (int t=0;t<24;t++)
    racc += Sf[L_PT + (g*24+t)*36 + col];
  racc += __shfl_xor(racc, 32);
  if (g == 0) out[(size_t)ray*32 + col] = 2.0f*racc - 1.0f;
  if (lane == 0){
    out[OFF_DEPTH+ray] = dp;
    out[OFF_WSUM+ray]  = wp;
  }
}

extern "C" void kernel_launch(void* const* d_in, const int* in_sizes, int n_in,
                              void* d_out, int out_size, void* d_ws, size_t ws_size,
                              hipStream_t stream){
  const float* planes = (const float*)d_in[0];
  const float* orig   = (const float*)d_in[1];
  const float* dirs   = (const float*)d_in[2];
  const float* w1     = (const float*)d_in[3];
  const float* b1     = (const float*)d_in[4];
  const float* w2     = (const float*)d_in[5];
  const float* b2     = (const float*)d_in[6];
  float* out = (float*)d_out;
  char*  ws  = (char*)d_ws;

  f16*   pT    = (f16*)(ws + PT_B);
  f16*   rgbc  = (f16*)(ws + RGBC_B);
  f16*   rgbf  = (f16*)(ws + RGBF_B);
  float* sigf  = (float*)(ws + SIGF_B);
  float* tfine = (float*)(ws + TFINE_B);
  f16*   w1A   = (f16*)(ws + W1A_B);
  float* b1F   = (float*)(ws + B1F_B);
  f16*   w2A   = (f16*)(ws + W2A_B);
  float* b2F   = (float*)(ws + B2F_B);

  k_transpose<<<dim3(NB*3*HPX*HPX/256), dim3(256), 0, stream>>>(planes, pT);
  k_prep<<<dim3(1), dim3(256), 0, stream>>>(w1, b1, w2, b2, w1A, b1F, w2A, b2F);
  k_model<true><<<dim3(NRAY*SC/256), dim3(256), 0, stream>>>(
      pT, orig, dirs, (const uint4*)w1A, (const f32x4*)b1F, (const uint4*)w2A,
      (const f32x4*)b2F, (const float*)nullptr, rgbc, out + OFF_SDF);
  k_importance<<<dim3(NRAY/64), dim3(64), 0, stream>>>(out + OFF_SDF, tfine);
  k_model<false><<<dim3(NRAY*SF/256), dim3(256), 0, stream>>>(
      pT, orig, dirs, (const uint4*)w1A, (const f32x4*)b1F, (const uint4*)w2A,
      (const f32x4*)b2F, tfine, rgbf, sigf);
  k_final<<<dim3(NRAY/4), dim3(256), 0, stream>>>(
      out + OFF_SDF, rgbc, sigf, rgbf, tfine, out);
}

// Round 7
// 102.159 us; speedup vs baseline: 4.9112x; 1.1815x over previous
//
#include <hip/hip_runtime.h>
#include <cstddef>

#define NB 2
#define RPB 4096
#define NRAY (NB*RPB)          // 8192
#define SC 48
#define SF 48
#define CP 32
#define HPX 256
#define HID 64
#define NOUT 33

#define DTC (1.05f/47.0f)
#define TC0 (2.25f + 0.5f*(1.05f/47.0f))

// d_out layout (floats)
#define OFF_DEPTH (NRAY*32)            // 262144
#define OFF_WSUM  (OFF_DEPTH + NRAY)   // 270336
#define OFF_SDF   (OFF_WSUM + NRAY)    // 278528

// ws layout (BYTES)
#define PT_B     ((size_t)0)                    // planesT f16: 25,165,824 B
#define W1A_B    ((size_t)25165824)
#define B1F_B    ((size_t)25169920)
#define W2A_B    ((size_t)25174016)
#define B2F_B    ((size_t)25180160)

#define PL_BYTES ((size_t)HPX*HPX*CP*2)         // 4,194,304 bytes per (b,pl)

typedef _Float16 f16;
typedef _Float16 f16x2 __attribute__((ext_vector_type(2)));
typedef _Float16 f16x8 __attribute__((ext_vector_type(8)));
typedef float    f32x4 __attribute__((ext_vector_type(4)));

#define LOG2E 1.44269504f
#define LN2   0.69314718f
static __device__ __forceinline__ float fast_exp(float x){
  return __builtin_amdgcn_exp2f(x*LOG2E);
}
static __device__ __forceinline__ float softplus_f(float x){
  float e = __builtin_amdgcn_exp2f(-fabsf(x)*LOG2E);
  float l = __builtin_amdgcn_logf(1.0f + e)*LN2;
  return fmaxf(x, 0.0f) + l;
}
static __device__ __forceinline__ float fast_sigmoid_scaled(float a){
  float e = __builtin_amdgcn_exp2f(-a*LOG2E);
  return __builtin_amdgcn_rcpf(1.0f + e)*1.002f - 0.001f;
}
static __device__ __forceinline__ unsigned pack2(float a, float b){
  f16x2 h = { (f16)a, (f16)b };
  return __builtin_bit_cast(unsigned int, h);
}

// per-wave slab layout (words); h region overlaps march/CDF regions across
// disjoint phases: coarse-GEMM(h) -> importance(CDF) -> fine-GEMM(h) -> march(DM..COEF)
#define SL_DM   0     // 96 f
#define SL_SM   96    // 96 f
#define SL_SRC  192   // 96 u
#define SL_COEF 288   // 96 f
#define SL_CDF  384   // 46 f
#define SL_SIGC 1152  // 48 f
#define SL_TF   1200  // 48 f
#define SL_SIGF 1248  // 48 f
#define SL_WORDS 1344

// planes (b,pl,c,y,x) f32 -> planesT (b,pl,y,x,c) f16; last block does frag prep
__global__ __launch_bounds__(256) void k_transpose_prep(
    const float* __restrict__ src,
    const float* __restrict__ w1, const float* __restrict__ b1,
    const float* __restrict__ w2, const float* __restrict__ b2,
    f16* __restrict__ dst,
    f16* __restrict__ w1A, float* __restrict__ b1F,
    f16* __restrict__ w2A, float* __restrict__ b2F)
{
  if (blockIdx.x == 1536){
    int tid = threadIdx.x;
    {
      int m = tid>>6, lane = tid&63, q = lane>>4, r16 = lane&15;
      #pragma unroll
      for (int j=0;j<8;j++){
        int c = q*8+j, i = m*16+r16;
        w1A[(m*64+lane)*8+j] = (f16)(w1[c*HID+i]*(1.0f/3.0f));
      }
      #pragma unroll
      for (int r=0;r<4;r++) b1F[(m*64+lane)*4+r] = b1[m*16+q*4+r];
    }
    for (int idx=tid; idx<384; idx+=256){
      int f = idx>>6, lane = idx&63, q = lane>>4, r16 = lane&15;
      int kc = f/3, m2 = f - kc*3;
      int row = m2*16+r16;
      int col = (row<32)? (row+1) : ((row==32)? 0 : -1);
      #pragma unroll
      for (int j=0;j<8;j++){
        int k = kc*32+q*8+j;
        w2A[(f*64+lane)*8+j] = (col>=0)? (f16)w2[k*NOUT+col] : (f16)0.0f;
      }
    }
    if (tid<192){
      int m2 = tid>>6, lane = tid&63, q = lane>>4;
      #pragma unroll
      for (int r=0;r<4;r++){
        int row = m2*16+q*4+r;
        float v = (row<32)? b2[row+1] : ((row==32)? b2[0] : 0.0f);
        b2F[(m2*64+lane)*4+r] = v;
      }
    }
    return;
  }
  int idx = blockIdx.x*256 + threadIdx.x;
  int xy = idx & (HPX*HPX-1);
  int bp = idx >> 16;
  const float* s = src + (size_t)bp*CP*HPX*HPX + xy;
  unsigned int w[16];
  #pragma unroll
  for (int c=0;c<CP;c+=2){
    w[c>>1] = pack2(s[(size_t)c*HPX*HPX], s[(size_t)(c+1)*HPX*HPX]);
  }
  uint4* d4 = reinterpret_cast<uint4*>(dst + (size_t)idx*CP);
  d4[0] = make_uint4(w[0],w[1],w[2],w[3]);
  d4[1] = make_uint4(w[4],w[5],w[6],w[7]);
  d4[2] = make_uint4(w[8],w[9],w[10],w[11]);
  d4[3] = make_uint4(w[12],w[13],w[14],w[15]);
}

// one-ray 48-point model eval: gather -> GEMM1 -> softplus -> GEMM2.
// sigma -> slab[sigOff + k]; rgb (sigmoided, f16-packed) -> rgbPk[12] registers.
static __device__ __forceinline__ void model48(
    const char* __restrict__ pb0,
    float ox,float oy,float oz,float dx,float dy,float dz,float t,
    const uint4* __restrict__ w1A, const f32x4* __restrict__ b1F,
    const uint4* __restrict__ w2A, const f32x4* __restrict__ b2F,
    unsigned* __restrict__ fb, float* __restrict__ fbF,
    int lane, int q, int c16,
    unsigned* rgbPk, int sigOff)
{
  // records for own point (lane = sample index; lanes 48-63 produce unused junk)
  unsigned wrec[3][4]; unsigned crec[3];
  {
    float cx = fmaf(t,dx,ox), cy = fmaf(t,dy,oy), cz = fmaf(t,dz,oz);
    #pragma unroll
    for (int pl=0; pl<3; pl++){
      float u = (pl==2)? cz : cx;
      float v = (pl==0)? cy : (pl==1 ? cz : cx);
      float x = ((u+1.0f)*256.0f - 1.0f)*0.5f;
      float y = ((v+1.0f)*256.0f - 1.0f)*0.5f;
      float xf = floorf(x), yf = floorf(y);
      float wx = x-xf, wy = y-yf;
      int ix = (int)xf, iy = (int)yf;
      int x0 = min(max(ix,0),HPX-1),   x1 = min(max(ix+1,0),HPX-1);
      int y0 = min(max(iy,0),HPX-1),   y1 = min(max(iy+1,0),HPX-1);
      float vx0 = ((unsigned)ix    < (unsigned)HPX) ? 1.f : 0.f;
      float vx1 = ((unsigned)(ix+1)< (unsigned)HPX) ? 1.f : 0.f;
      float vy0 = ((unsigned)iy    < (unsigned)HPX) ? 1.f : 0.f;
      float vy1 = ((unsigned)(iy+1)< (unsigned)HPX) ? 1.f : 0.f;
      float w00 = (1.f-wx)*(1.f-wy)*vx0*vy0;
      float w01 = wx*(1.f-wy)*vx1*vy0;
      float w10 = (1.f-wx)*wy*vx0*vy1;
      float w11 = wx*wy*vx1*vy1;
      wrec[pl][0] = pack2(w00,w00);
      wrec[pl][1] = pack2(w01,w01);
      wrec[pl][2] = pack2(w10,w10);
      wrec[pl][3] = pack2(w11,w11);
      crec[pl] = (unsigned)x0 | ((unsigned)x1<<8) | ((unsigned)y0<<16) | ((unsigned)y1<<24);
    }
  }

  // cooperative gather: lane(q,c16) accumulates channels 8q..8q+7 of points s*16+c16
  f16x2 fs[3][4];
  #pragma unroll
  for (int s=0;s<3;s++)
    #pragma unroll
    for (int j=0;j<4;j++) fs[s][j] = (f16x2){(f16)0.0f,(f16)0.0f};

  int qoff = q*16;
  #pragma unroll
  for (int s=0;s<3;s++){
    int srcl = s*16 + c16;
    unsigned rw[12], rc[3];
    #pragma unroll
    for (int pl=0;pl<3;pl++){
      #pragma unroll
      for (int k=0;k<4;k++)
        rw[pl*4+k] = (unsigned)__shfl((int)wrec[pl][k], srcl);
      rc[pl] = (unsigned)__shfl((int)crec[pl], srcl);
    }
    int offs[12];
    #pragma unroll
    for (int pl=0;pl<3;pl++){
      unsigned crd = rc[pl];
      int x0 = crd & 255, x1 = (crd>>8) & 255;
      int y0 = (crd>>16) & 255, y1 = crd>>24;
      int pbase = (int)(pl*(int)PL_BYTES);
      offs[pl*4+0] = pbase + (y0<<14)+(x0<<6)+qoff;
      offs[pl*4+1] = pbase + (y0<<14)+(x1<<6)+qoff;
      offs[pl*4+2] = pbase + (y1<<14)+(x0<<6)+qoff;
      offs[pl*4+3] = pbase + (y1<<14)+(x1<<6)+qoff;
    }
    uint4 L[12];
    #pragma unroll
    for (int j=0;j<12;j++)
      L[j] = *reinterpret_cast<const uint4*>(pb0 + offs[j]);
    #pragma unroll
    for (int j=0;j<12;j++){
      f16x2 wv2 = __builtin_bit_cast(f16x2, rw[j]);
      fs[s][0] += __builtin_bit_cast(f16x2, L[j].x) * wv2;
      fs[s][1] += __builtin_bit_cast(f16x2, L[j].y) * wv2;
      fs[s][2] += __builtin_bit_cast(f16x2, L[j].z) * wv2;
      fs[s][3] += __builtin_bit_cast(f16x2, L[j].w) * wv2;
    }
  }

  f16x8 bfr[3];
  #pragma unroll
  for (int n=0;n<3;n++){
    uint4 u = make_uint4(__builtin_bit_cast(unsigned, fs[n][0]),
                         __builtin_bit_cast(unsigned, fs[n][1]),
                         __builtin_bit_cast(unsigned, fs[n][2]),
                         __builtin_bit_cast(unsigned, fs[n][3]));
    bfr[n] = __builtin_bit_cast(f16x8, u);
  }

  f32x4 acc2[3][3];
  #pragma unroll
  for (int m2=0;m2<3;m2++){
    f32x4 binit = b2F[m2*64+lane];
    #pragma unroll
    for (int n=0;n<3;n++) acc2[m2][n] = binit;
  }

  #pragma unroll
  for (int half=0; half<2; half++){
    f16x8 a0 = __builtin_bit_cast(f16x8, w1A[(2*half+0)*64+lane]);
    f16x8 a1 = __builtin_bit_cast(f16x8, w1A[(2*half+1)*64+lane]);
    f32x4 i0 = b1F[(2*half+0)*64+lane];
    f32x4 i1 = b1F[(2*half+1)*64+lane];
    f32x4 accA[3], accB[3];
    #pragma unroll
    for (int n=0;n<3;n++){
      accA[n] = __builtin_amdgcn_mfma_f32_16x16x32_f16(a0, bfr[n], i0, 0,0,0);
      accB[n] = __builtin_amdgcn_mfma_f32_16x16x32_f16(a1, bfr[n], i1, 0,0,0);
    }
    #pragma unroll
    for (int n=0;n<3;n++){
      int P = n*16 + c16;
      uint2 vA, vB;
      vA.x = pack2(softplus_f(accA[n][0]), softplus_f(accA[n][1]));
      vA.y = pack2(softplus_f(accA[n][2]), softplus_f(accA[n][3]));
      vB.x = pack2(softplus_f(accB[n][0]), softplus_f(accB[n][1]));
      vB.y = pack2(softplus_f(accB[n][2]), softplus_f(accB[n][3]));
      *reinterpret_cast<uint2*>(&fb[P*18 + 0 + q*2]) = vA;
      *reinterpret_cast<uint2*>(&fb[P*18 + 8 + q*2]) = vB;
    }
    f16x8 b2f[3];
    #pragma unroll
    for (int n=0;n<3;n++){
      int P = n*16 + c16;
      uint4 u = *reinterpret_cast<const uint4*>(&fb[P*18 + q*4]);
      b2f[n] = __builtin_bit_cast(f16x8, u);
    }
    #pragma unroll
    for (int m2=0;m2<3;m2++){
      f16x8 a = __builtin_bit_cast(f16x8, w2A[(half*3+m2)*64+lane]);
      #pragma unroll
      for (int n=0;n<3;n++)
        acc2[m2][n] = __builtin_amdgcn_mfma_f32_16x16x32_f16(a, b2f[n], acc2[m2][n], 0,0,0);
    }
  }

  // sigma row 32 = (m2=2, q=0, r=0)
  if (q==0){
    #pragma unroll
    for (int n=0;n<3;n++) fbF[sigOff + n*16 + c16] = acc2[2][n][0];
  }
  // rgb rows 0..31 (sigmoid, pack)
  #pragma unroll
  for (int m2=0;m2<2;m2++){
    #pragma unroll
    for (int n=0;n<3;n++){
      f32x4 v = acc2[m2][n];
      rgbPk[(m2*3+n)*2+0] = pack2(fast_sigmoid_scaled(v[0]), fast_sigmoid_scaled(v[1]));
      rgbPk[(m2*3+n)*2+1] = pack2(fast_sigmoid_scaled(v[2]), fast_sigmoid_scaled(v[3]));
    }
  }
}

// one wave = one ray: coarse model -> importance -> fine model -> merge+march
__global__ __launch_bounds__(256, 3) void k_render(
    const f16* __restrict__ pT,
    const float* __restrict__ orig,
    const float* __restrict__ dirs,
    const uint4* __restrict__ w1A,
    const f32x4* __restrict__ b1F,
    const uint4* __restrict__ w2A,
    const f32x4* __restrict__ b2F,
    float* __restrict__ out)
{
  __shared__ unsigned int lds[4][SL_WORDS];
  int tid = threadIdx.x;
  int lane = tid & 63;
  int wv = tid >> 6;
  int ray = blockIdx.x*4 + wv;
  unsigned* S = &lds[wv][0];
  float* Sf = (float*)S;
  int q = lane >> 4;
  int c16 = lane & 15;

  int bb = ray >> 12;
  const char* pb0 = (const char*)pT + (size_t)(bb*3)*PL_BYTES;
  float ox = orig[ray*3+0], oy = orig[ray*3+1], oz = orig[ray*3+2];
  float dx = dirs[ray*3+0], dy = dirs[ray*3+1], dz = dirs[ray*3+2];

  unsigned rgbC[12], rgbF[12];

  // ---- coarse pass ----
  float tC = TC0 + (float)min(lane,47)*DTC;
  model48(pb0, ox,oy,oz,dx,dy,dz, tC, w1A,b1F,w2A,b2F, S, Sf, lane,q,c16, rgbC, SL_SIGC);
  if (lane < 48) out[OFF_SDF + (size_t)ray*48 + lane] = Sf[SL_SIGC+lane];

  // ---- importance resample (wave-parallel) ----
  {
    float sk  = Sf[SL_SIGC + min(lane,47)];
    float sk1 = Sf[SL_SIGC + min(lane+1,47)];
    float alpha = 0.f, g = 1.f;
    if (lane < 47){
      float dm = softplus_f(0.5f*(sk+sk1)-1.0f);
      alpha = 1.0f - fast_exp(-dm*DTC);
      g = 1.0f - alpha + 1e-10f;
    }
    float ip = g;
    #pragma unroll
    for (int off=1; off<64; off<<=1){ float v=__shfl_up(ip,off); if(lane>=off) ip*=v; }
    float T = __shfl_up(ip,1); if (lane==0) T = 1.0f;
    float wk = alpha*T;
    float wm1 = __shfl_up(wk,1);   if (lane==0) wm1 = 0.f;
    float wp1 = __shfl_down(wk,1);
    float qv = 0.5f*(fmaxf(wm1,wk)+fmaxf(wk,wp1)) + 0.01f;
    float qs = (lane>=1 && lane<=45)? qv : 0.0f;
    float sum = qs;
    #pragma unroll
    for (int off=1; off<64; off<<=1) sum += __shfl_xor(sum,off);
    float cs = qs;
    #pragma unroll
    for (int off=1; off<64; off<<=1){ float v=__shfl_up(cs,off); if(lane>=off) cs+=v; }
    float C = cs/sum;
    if (lane < 46) Sf[SL_CDF+lane] = C;
    float u = (float)lane/47.0f;
    int pos = 0;
    #pragma unroll
    for (int st=32; st>=1; st>>=1){
      int np = pos+st;
      if (np<=45 && Sf[SL_CDF+np] <= u) pos = np;
    }
    int ab = min(pos+1,45);
    float cb = Sf[SL_CDF+pos];
    float ca = Sf[SL_CDF+ab];
    float bbz = TC0 + ((float)pos+0.5f)*DTC;
    float baz = TC0 + ((float)ab +0.5f)*DTC;
    float denom = ca - cb;
    if (denom < 1e-5f) denom = 1.0f;
    float tf = bbz + (u-cb)/denom*(baz-bbz);
    if (lane < 48) Sf[SL_TF+lane] = tf;
  }

  // ---- fine pass ----
  float tF = Sf[SL_TF + min(lane,47)];
  model48(pb0, ox,oy,oz,dx,dy,dz, tF, w1A,b1F,w2A,b2F, S, Sf, lane,q,c16, rgbF, SL_SIGF);

  // ---- merge ranks (stable: coarse first on tie) ----
  if (lane < 48){
    float dcv = TC0 + (float)lane*DTC;
    int pos = 0;
    #pragma unroll
    for (int stp=32; stp>=1; stp>>=1){
      int np = pos + stp;
      if (np <= 48 && Sf[SL_TF+np-1] < dcv) pos = np;
    }
    int rank_c = lane + pos;
    Sf[SL_DM+rank_c] = dcv;
    Sf[SL_SM+rank_c] = Sf[SL_SIGC+lane];
    S [SL_SRC+rank_c] = lane;
    float x = Sf[SL_TF+lane];
    int cnt = (int)(floorf((x - TC0)*(1.0f/DTC)) + 1.0f);
    cnt = min(max(cnt,0),48);
    while (cnt < 48 && (TC0 + (float)cnt*DTC) <= x) cnt++;
    while (cnt > 0 && (TC0 + (float)(cnt-1)*DTC) > x) cnt--;
    int rank_f = lane + cnt;
    Sf[SL_DM+rank_f] = x;
    Sf[SL_SM+rank_f] = Sf[SL_SIGF+lane];
    S [SL_SRC+rank_f] = 48 + lane;
  }

  // ---- march: per-lane 2 samples, product scan, coefficients ----
  int s0 = 2*lane, s1 = s0+1;
  float alpha0=0.f, alpha1=0.f, g0=1.f, g1=1.f;
  float d0=0.f, d1=0.f, d2=0.f;
  if (lane < 48){
    int s2i = min(s1+1, 95);
    d0 = Sf[SL_DM+s0]; d1 = Sf[SL_DM+s1]; d2 = Sf[SL_DM+s2i];
    float m0 = Sf[SL_SM+s0], m1 = Sf[SL_SM+s1], m2v = Sf[SL_SM+s2i];
    {
      float dm = softplus_f(0.5f*(m0+m1)-1.0f);
      alpha0 = 1.0f - fast_exp(-dm*(d1-d0));
      g0 = 1.0f - alpha0 + 1e-10f;
    }
    if (lane < 47){
      float dm = softplus_f(0.5f*(m1+m2v)-1.0f);
      alpha1 = 1.0f - fast_exp(-dm*(d2-d1));
      g1 = 1.0f - alpha1 + 1e-10f;
    }
  }
  float ip = g0*g1;
  #pragma unroll
  for (int off=1; off<64; off<<=1){
    float v = __shfl_up(ip, off);
    if (lane >= off) ip *= v;
  }
  float E = __shfl_up(ip, 1);
  if (lane == 0) E = 1.0f;
  float w0 = alpha0*E;
  float w1v = alpha1*E*g0;
  float wprev = __shfl_up(w1v, 1);
  if (lane == 0) wprev = 0.0f;
  float coef0 = 0.5f*(wprev + w0);
  float coef1 = 0.5f*(w0 + w1v);
  float dp = (lane<48) ? (w0*0.5f*(d0+d1) + w1v*0.5f*(d1+d2)) : 0.f;
  float wp = w0 + w1v;

  if (lane < 48){
    int src0 = (int)S[SL_SRC+s0], src1 = (int)S[SL_SRC+s1];
    Sf[SL_COEF+src0] = coef0;
    Sf[SL_COEF+src1] = coef1;
  }

  #pragma unroll
  for (int off=1; off<64; off<<=1){
    dp += __shfl_xor(dp, off);
    wp += __shfl_xor(wp, off);
  }

  // ---- color sum in MFMA C-layout, reduce over c16 ----
  float cc[8] = {0.f,0.f,0.f,0.f,0.f,0.f,0.f,0.f};
  #pragma unroll
  for (int n=0;n<3;n++){
    int pt = n*16 + c16;
    float cfC = Sf[SL_COEF + pt];
    float cfF = Sf[SL_COEF + 48 + pt];
    #pragma unroll
    for (int m2=0;m2<2;m2++){
      #pragma unroll
      for (int hw=0; hw<2; hw++){
        f16x2 hc = __builtin_bit_cast(f16x2, rgbC[(m2*3+n)*2+hw]);
        f16x2 hf = __builtin_bit_cast(f16x2, rgbF[(m2*3+n)*2+hw]);
        cc[m2*4+hw*2+0] += cfC*(float)hc[0] + cfF*(float)hf[0];
        cc[m2*4+hw*2+1] += cfC*(float)hc[1] + cfF*(float)hf[1];
      }
    }
  }
  #pragma unroll
  for (int off=1; off<16; off<<=1){
    #pragma unroll
    for (int i=0;i<8;i++) cc[i] += __shfl_xor(cc[i], off);
  }
  if (c16 == 0){
    #pragma unroll
    for (int m2=0;m2<2;m2++){
      f32x4 o4;
      #pragma unroll
      for (int r=0;r<4;r++) o4[r] = 2.0f*cc[m2*4+r] - 1.0f;
      *reinterpret_cast<f32x4*>(&out[(size_t)ray*32 + m2*16 + q*4]) = o4;
    }
  }
  if (lane == 0){
    out[OFF_DEPTH+ray] = dp;
    out[OFF_WSUM+ray]  = wp;
  }
}

extern "C" void kernel_launch(void* const* d_in, const int* in_sizes, int n_in,
                              void* d_out, int out_size, void* d_ws, size_t ws_size,
                              hipStream_t stream){
  const float* planes = (const float*)d_in[0];
  const float* orig   = (const float*)d_in[1];
  const float* dirs   = (const float*)d_in[2];
  const float* w1     = (const float*)d_in[3];
  const float* b1     = (const float*)d_in[4];
  const float* w2     = (const float*)d_in[5];
  const float* b2     = (const float*)d_in[6];
  float* out = (float*)d_out;
  char*  ws  = (char*)d_ws;

  f16*   pT    = (f16*)(ws + PT_B);
  f16*   w1A   = (f16*)(ws + W1A_B);
  float* b1F   = (float*)(ws + B1F_B);
  f16*   w2A   = (f16*)(ws + W2A_B);
  float* b2F   = (float*)(ws + B2F_B);

  k_transpose_prep<<<dim3(1537), dim3(256), 0, stream>>>(
      planes, w1, b1, w2, b2, pT, w1A, b1F, w2A, b2F);
  k_render<<<dim3(NRAY/4), dim3(256), 0, stream>>>(
      pT, orig, dirs, (const uint4*)w1A, (const f32x4*)b1F,
      (const uint4*)w2A, (const f32x4*)b2F, out);
}

// Round 8
// 89.809 us; speedup vs baseline: 5.5866x; 1.1375x over previous
//
#include <hip/hip_runtime.h>
#include <cstddef>

#define NB 2
#define RPB 4096
#define NRAY (NB*RPB)          // 8192
#define SC 48
#define SF 48
#define CP 32
#define HPX 256
#define HID 64
#define NOUT 33

#define DTC (1.05f/47.0f)
#define TC0 (2.25f + 0.5f*(1.05f/47.0f))

// d_out layout (floats)
#define OFF_DEPTH (NRAY*32)            // 262144
#define OFF_WSUM  (OFF_DEPTH + NRAY)   // 270336
#define OFF_SDF   (OFF_WSUM + NRAY)    // 278528

// ws layout (BYTES)
#define PT_B     ((size_t)0)                    // planesT f16: 25,165,824 B
#define W1A_B    ((size_t)25165824)
#define B1F_B    ((size_t)25169920)
#define W2A_B    ((size_t)25174016)
#define B2F_B    ((size_t)25180160)

#define PL_BYTES ((size_t)HPX*HPX*CP*2)         // 4,194,304 bytes per (b,pl)

typedef _Float16 f16;
typedef _Float16 f16x2 __attribute__((ext_vector_type(2)));
typedef _Float16 f16x8 __attribute__((ext_vector_type(8)));
typedef float    f32x4 __attribute__((ext_vector_type(4)));

#define LOG2E 1.44269504f
#define LN2   0.69314718f
static __device__ __forceinline__ float fast_exp(float x){
  return __builtin_amdgcn_exp2f(x*LOG2E);
}
static __device__ __forceinline__ float softplus_f(float x){
  float e = __builtin_amdgcn_exp2f(-fabsf(x)*LOG2E);
  float l = __builtin_amdgcn_logf(1.0f + e)*LN2;
  return fmaxf(x, 0.0f) + l;
}
static __device__ __forceinline__ float fast_sigmoid_scaled(float a){
  float e = __builtin_amdgcn_exp2f(-a*LOG2E);
  return __builtin_amdgcn_rcpf(1.0f + e)*1.002f - 0.001f;
}
static __device__ __forceinline__ unsigned pack2(float a, float b){
  f16x2 h = { (f16)a, (f16)b };
  return __builtin_bit_cast(unsigned int, h);
}

// per-wave slab layout (words)
#define SL_DM   0     // 96 f
#define SL_SM   96    // 96 f
#define SL_SRC  192   // 96 u
#define SL_COEF 288   // 96 f
#define SL_CDF  384   // 46 f
#define SL_SIGC 1152  // 48 f
#define SL_TF   1200  // 48 f
#define SL_SIGF 1248  // 48 f
#define SL_WORDS 1344

// planes (b,pl,c,y,x) f32 -> planesT (b,pl,y,x,c) f16; last block does frag prep
__global__ __launch_bounds__(256) void k_transpose_prep(
    const float* __restrict__ src,
    const float* __restrict__ w1, const float* __restrict__ b1,
    const float* __restrict__ w2, const float* __restrict__ b2,
    f16* __restrict__ dst,
    f16* __restrict__ w1A, float* __restrict__ b1F,
    f16* __restrict__ w2A, float* __restrict__ b2F)
{
  if (blockIdx.x == 1536){
    int tid = threadIdx.x;
    {
      int m = tid>>6, lane = tid&63, q = lane>>4, r16 = lane&15;
      #pragma unroll
      for (int j=0;j<8;j++){
        int c = q*8+j, i = m*16+r16;
        w1A[(m*64+lane)*8+j] = (f16)(w1[c*HID+i]*(1.0f/3.0f));
      }
      #pragma unroll
      for (int r=0;r<4;r++) b1F[(m*64+lane)*4+r] = b1[m*16+q*4+r];
    }
    for (int idx=tid; idx<384; idx+=256){
      int f = idx>>6, lane = idx&63, q = lane>>4, r16 = lane&15;
      int kc = f/3, m2 = f - kc*3;
      int row = m2*16+r16;
      int col = (row<32)? (row+1) : ((row==32)? 0 : -1);
      #pragma unroll
      for (int j=0;j<8;j++){
        int k = kc*32+q*8+j;
        w2A[(f*64+lane)*8+j] = (col>=0)? (f16)w2[k*NOUT+col] : (f16)0.0f;
      }
    }
    if (tid<192){
      int m2 = tid>>6, lane = tid&63, q = lane>>4;
      #pragma unroll
      for (int r=0;r<4;r++){
        int row = m2*16+q*4+r;
        float v = (row<32)? b2[row+1] : ((row==32)? b2[0] : 0.0f);
        b2F[(m2*64+lane)*4+r] = v;
      }
    }
    return;
  }
  int idx = blockIdx.x*256 + threadIdx.x;
  int xy = idx & (HPX*HPX-1);
  int bp = idx >> 16;
  const float* s = src + (size_t)bp*CP*HPX*HPX + xy;
  unsigned int w[16];
  #pragma unroll
  for (int c=0;c<CP;c+=2){
    w[c>>1] = pack2(s[(size_t)c*HPX*HPX], s[(size_t)(c+1)*HPX*HPX]);
  }
  uint4* d4 = reinterpret_cast<uint4*>(dst + (size_t)idx*CP);
  d4[0] = make_uint4(w[0],w[1],w[2],w[3]);
  d4[1] = make_uint4(w[4],w[5],w[6],w[7]);
  d4[2] = make_uint4(w[8],w[9],w[10],w[11]);
  d4[3] = make_uint4(w[12],w[13],w[14],w[15]);
}

// one-ray 48-point model eval: gather -> GEMM1 -> softplus -> GEMM2.
static __device__ __forceinline__ void model48(
    const char* __restrict__ pb0,
    float ox,float oy,float oz,float dx,float dy,float dz,float t,
    const uint4* __restrict__ w1A, const f32x4* __restrict__ b1F,
    const uint4* __restrict__ w2A, const f32x4* __restrict__ b2F,
    unsigned* __restrict__ fb, float* __restrict__ fbF,
    int lane, int q, int c16,
    unsigned* rgbPk, int sigOff)
{
  unsigned wrec[3][4]; unsigned crec[3];
  {
    float cx = fmaf(t,dx,ox), cy = fmaf(t,dy,oy), cz = fmaf(t,dz,oz);
    #pragma unroll
    for (int pl=0; pl<3; pl++){
      float u = (pl==2)? cz : cx;
      float v = (pl==0)? cy : (pl==1 ? cz : cx);
      float x = ((u+1.0f)*256.0f - 1.0f)*0.5f;
      float y = ((v+1.0f)*256.0f - 1.0f)*0.5f;
      float xf = floorf(x), yf = floorf(y);
      float wx = x-xf, wy = y-yf;
      int ix = (int)xf, iy = (int)yf;
      int x0 = min(max(ix,0),HPX-1),   x1 = min(max(ix+1,0),HPX-1);
      int y0 = min(max(iy,0),HPX-1),   y1 = min(max(iy+1,0),HPX-1);
      float vx0 = ((unsigned)ix    < (unsigned)HPX) ? 1.f : 0.f;
      float vx1 = ((unsigned)(ix+1)< (unsigned)HPX) ? 1.f : 0.f;
      float vy0 = ((unsigned)iy    < (unsigned)HPX) ? 1.f : 0.f;
      float vy1 = ((unsigned)(iy+1)< (unsigned)HPX) ? 1.f : 0.f;
      float w00 = (1.f-wx)*(1.f-wy)*vx0*vy0;
      float w01 = wx*(1.f-wy)*vx1*vy0;
      float w10 = (1.f-wx)*wy*vx0*vy1;
      float w11 = wx*wy*vx1*vy1;
      wrec[pl][0] = pack2(w00,w00);
      wrec[pl][1] = pack2(w01,w01);
      wrec[pl][2] = pack2(w10,w10);
      wrec[pl][3] = pack2(w11,w11);
      crec[pl] = (unsigned)x0 | ((unsigned)x1<<8) | ((unsigned)y0<<16) | ((unsigned)y1<<24);
    }
  }

  f16x2 fs[3][4];
  #pragma unroll
  for (int s=0;s<3;s++)
    #pragma unroll
    for (int j=0;j<4;j++) fs[s][j] = (f16x2){(f16)0.0f,(f16)0.0f};

  int qoff = q*16;
  #pragma unroll
  for (int s=0;s<3;s++){
    int srcl = s*16 + c16;
    unsigned rw[12], rc[3];
    #pragma unroll
    for (int pl=0;pl<3;pl++){
      #pragma unroll
      for (int k=0;k<4;k++)
        rw[pl*4+k] = (unsigned)__shfl((int)wrec[pl][k], srcl);
      rc[pl] = (unsigned)__shfl((int)crec[pl], srcl);
    }
    int offs[12];
    #pragma unroll
    for (int pl=0;pl<3;pl++){
      unsigned crd = rc[pl];
      int x0 = crd & 255, x1 = (crd>>8) & 255;
      int y0 = (crd>>16) & 255, y1 = crd>>24;
      int pbase = (int)(pl*(int)PL_BYTES);
      offs[pl*4+0] = pbase + (y0<<14)+(x0<<6)+qoff;
      offs[pl*4+1] = pbase + (y0<<14)+(x1<<6)+qoff;
      offs[pl*4+2] = pbase + (y1<<14)+(x0<<6)+qoff;
      offs[pl*4+3] = pbase + (y1<<14)+(x1<<6)+qoff;
    }
    uint4 L[12];
    #pragma unroll
    for (int j=0;j<12;j++)
      L[j] = *reinterpret_cast<const uint4*>(pb0 + offs[j]);
    #pragma unroll
    for (int j=0;j<12;j++){
      f16x2 wv2 = __builtin_bit_cast(f16x2, rw[j]);
      fs[s][0] += __builtin_bit_cast(f16x2, L[j].x) * wv2;
      fs[s][1] += __builtin_bit_cast(f16x2, L[j].y) * wv2;
      fs[s][2] += __builtin_bit_cast(f16x2, L[j].z) * wv2;
      fs[s][3] += __builtin_bit_cast(f16x2, L[j].w) * wv2;
    }
  }

  f16x8 bfr[3];
  #pragma unroll
  for (int n=0;n<3;n++){
    uint4 u = make_uint4(__builtin_bit_cast(unsigned, fs[n][0]),
                         __builtin_bit_cast(unsigned, fs[n][1]),
                         __builtin_bit_cast(unsigned, fs[n][2]),
                         __builtin_bit_cast(unsigned, fs[n][3]));
    bfr[n] = __builtin_bit_cast(f16x8, u);
  }

  f32x4 acc2[3][3];
  #pragma unroll
  for (int m2=0;m2<3;m2++){
    f32x4 binit = b2F[m2*64+lane];
    #pragma unroll
    for (int n=0;n<3;n++) acc2[m2][n] = binit;
  }

  #pragma unroll
  for (int half=0; half<2; half++){
    f16x8 a0 = __builtin_bit_cast(f16x8, w1A[(2*half+0)*64+lane]);
    f16x8 a1 = __builtin_bit_cast(f16x8, w1A[(2*half+1)*64+lane]);
    f32x4 i0 = b1F[(2*half+0)*64+lane];
    f32x4 i1 = b1F[(2*half+1)*64+lane];
    f32x4 accA[3], accB[3];
    #pragma unroll
    for (int n=0;n<3;n++){
      accA[n] = __builtin_amdgcn_mfma_f32_16x16x32_f16(a0, bfr[n], i0, 0,0,0);
      accB[n] = __builtin_amdgcn_mfma_f32_16x16x32_f16(a1, bfr[n], i1, 0,0,0);
    }
    #pragma unroll
    for (int n=0;n<3;n++){
      int P = n*16 + c16;
      uint2 vA, vB;
      vA.x = pack2(softplus_f(accA[n][0]), softplus_f(accA[n][1]));
      vA.y = pack2(softplus_f(accA[n][2]), softplus_f(accA[n][3]));
      vB.x = pack2(softplus_f(accB[n][0]), softplus_f(accB[n][1]));
      vB.y = pack2(softplus_f(accB[n][2]), softplus_f(accB[n][3]));
      *reinterpret_cast<uint2*>(&fb[P*18 + 0 + q*2]) = vA;
      *reinterpret_cast<uint2*>(&fb[P*18 + 8 + q*2]) = vB;
    }
    f16x8 b2f[3];
    #pragma unroll
    for (int n=0;n<3;n++){
      int P = n*16 + c16;
      uint4 u = *reinterpret_cast<const uint4*>(&fb[P*18 + q*4]);
      b2f[n] = __builtin_bit_cast(f16x8, u);
    }
    #pragma unroll
    for (int m2=0;m2<3;m2++){
      f16x8 a = __builtin_bit_cast(f16x8, w2A[(half*3+m2)*64+lane]);
      #pragma unroll
      for (int n=0;n<3;n++)
        acc2[m2][n] = __builtin_amdgcn_mfma_f32_16x16x32_f16(a, b2f[n], acc2[m2][n], 0,0,0);
    }
  }

  if (q==0){
    #pragma unroll
    for (int n=0;n<3;n++) fbF[sigOff + n*16 + c16] = acc2[2][n][0];
  }
  #pragma unroll
  for (int m2=0;m2<2;m2++){
    #pragma unroll
    for (int n=0;n<3;n++){
      f32x4 v = acc2[m2][n];
      rgbPk[(m2*3+n)*2+0] = pack2(fast_sigmoid_scaled(v[0]), fast_sigmoid_scaled(v[1]));
      rgbPk[(m2*3+n)*2+1] = pack2(fast_sigmoid_scaled(v[2]), fast_sigmoid_scaled(v[3]));
    }
  }
}

// one wave = one ray
__global__ __launch_bounds__(256, 2) void k_render(
    const f16* __restrict__ pT,
    const float* __restrict__ orig,
    const float* __restrict__ dirs,
    const uint4* __restrict__ w1A,
    const f32x4* __restrict__ b1F,
    const uint4* __restrict__ w2A,
    const f32x4* __restrict__ b2F,
    float* __restrict__ out)
{
  __shared__ unsigned int lds[4][SL_WORDS];
  int tid = threadIdx.x;
  int lane = tid & 63;
  int wv = tid >> 6;
  int ray = blockIdx.x*4 + wv;
  unsigned* S = &lds[wv][0];
  float* Sf = (float*)S;
  int q = lane >> 4;
  int c16 = lane & 15;

  int bb = ray >> 12;
  const char* pb0 = (const char*)pT + (size_t)(bb*3)*PL_BYTES;
  float ox = orig[ray*3+0], oy = orig[ray*3+1], oz = orig[ray*3+2];
  float dx = dirs[ray*3+0], dy = dirs[ray*3+1], dz = dirs[ray*3+2];

  unsigned rgbC[12], rgbF[12];

  // ---- coarse pass ----
  float tC = TC0 + (float)min(lane,47)*DTC;
  model48(pb0, ox,oy,oz,dx,dy,dz, tC, w1A,b1F,w2A,b2F, S, Sf, lane,q,c16, rgbC, SL_SIGC);
  if (lane < 48) out[OFF_SDF + (size_t)ray*48 + lane] = Sf[SL_SIGC+lane];

  // ---- importance resample (wave-parallel) ----
  {
    float sk  = Sf[SL_SIGC + min(lane,47)];
    float sk1 = Sf[SL_SIGC + min(lane+1,47)];
    float alpha = 0.f, g = 1.f;
    if (lane < 47){
      float dm = softplus_f(0.5f*(sk+sk1)-1.0f);
      alpha = 1.0f - fast_exp(-dm*DTC);
      g = 1.0f - alpha + 1e-10f;
    }
    float ip = g;
    #pragma unroll
    for (int off=1; off<64; off<<=1){ float v=__shfl_up(ip,off); if(lane>=off) ip*=v; }
    float T = __shfl_up(ip,1); if (lane==0) T = 1.0f;
    float wk = alpha*T;
    float wm1 = __shfl_up(wk,1);   if (lane==0) wm1 = 0.f;
    float wp1 = __shfl_down(wk,1);
    float qv = 0.5f*(fmaxf(wm1,wk)+fmaxf(wk,wp1)) + 0.01f;
    float qs = (lane>=1 && lane<=45)? qv : 0.0f;
    float sum = qs;
    #pragma unroll
    for (int off=1; off<64; off<<=1) sum += __shfl_xor(sum,off);
    float cs = qs;
    #pragma unroll
    for (int off=1; off<64; off<<=1){ float v=__shfl_up(cs,off); if(lane>=off) cs+=v; }
    float C = cs/sum;
    if (lane < 46) Sf[SL_CDF+lane] = C;
    float u = (float)lane/47.0f;
    int pos = 0;
    #pragma unroll
    for (int st=32; st>=1; st>>=1){
      int np = pos+st;
      if (np<=45 && Sf[SL_CDF+np] <= u) pos = np;
    }
    int ab = min(pos+1,45);
    float cb = Sf[SL_CDF+pos];
    float ca = Sf[SL_CDF+ab];
    float bbz = TC0 + ((float)pos+0.5f)*DTC;
    float baz = TC0 + ((float)ab +0.5f)*DTC;
    float denom = ca - cb;
    if (denom < 1e-5f) denom = 1.0f;
    float tf = bbz + (u-cb)/denom*(baz-bbz);
    if (lane < 48) Sf[SL_TF+lane] = tf;
  }

  // ---- fine pass ----
  float tF = Sf[SL_TF + min(lane,47)];
  model48(pb0, ox,oy,oz,dx,dy,dz, tF, w1A,b1F,w2A,b2F, S, Sf, lane,q,c16, rgbF, SL_SIGF);

  // ---- merge ranks (stable: coarse first on tie) ----
  if (lane < 48){
    float dcv = TC0 + (float)lane*DTC;
    int pos = 0;
    #pragma unroll
    for (int stp=32; stp>=1; stp>>=1){
      int np = pos + stp;
      if (np <= 48 && Sf[SL_TF+np-1] < dcv) pos = np;
    }
    int rank_c = lane + pos;
    Sf[SL_DM+rank_c] = dcv;
    Sf[SL_SM+rank_c] = Sf[SL_SIGC+lane];
    S [SL_SRC+rank_c] = lane;
    float x = Sf[SL_TF+lane];
    int cnt = (int)(floorf((x - TC0)*(1.0f/DTC)) + 1.0f);
    cnt = min(max(cnt,0),48);
    while (cnt < 48 && (TC0 + (float)cnt*DTC) <= x) cnt++;
    while (cnt > 0 && (TC0 + (float)(cnt-1)*DTC) > x) cnt--;
    int rank_f = lane + cnt;
    Sf[SL_DM+rank_f] = x;
    Sf[SL_SM+rank_f] = Sf[SL_SIGF+lane];
    S [SL_SRC+rank_f] = 48 + lane;
  }

  // ---- march ----
  int s0 = 2*lane, s1 = s0+1;
  float alpha0=0.f, alpha1=0.f, g0=1.f, g1=1.f;
  float d0=0.f, d1=0.f, d2=0.f;
  if (lane < 48){
    int s2i = min(s1+1, 95);
    d0 = Sf[SL_DM+s0]; d1 = Sf[SL_DM+s1]; d2 = Sf[SL_DM+s2i];
    float m0 = Sf[SL_SM+s0], m1 = Sf[SL_SM+s1], m2v = Sf[SL_SM+s2i];
    {
      float dm = softplus_f(0.5f*(m0+m1)-1.0f);
      alpha0 = 1.0f - fast_exp(-dm*(d1-d0));
      g0 = 1.0f - alpha0 + 1e-10f;
    }
    if (lane < 47){
      float dm = softplus_f(0.5f*(m1+m2v)-1.0f);
      alpha1 = 1.0f - fast_exp(-dm*(d2-d1));
      g1 = 1.0f - alpha1 + 1e-10f;
    }
  }
  float ip = g0*g1;
  #pragma unroll
  for (int off=1; off<64; off<<=1){
    float v = __shfl_up(ip, off);
    if (lane >= off) ip *= v;
  }
  float E = __shfl_up(ip, 1);
  if (lane == 0) E = 1.0f;
  float w0 = alpha0*E;
  float w1v = alpha1*E*g0;
  float wprev = __shfl_up(w1v, 1);
  if (lane == 0) wprev = 0.0f;
  float coef0 = 0.5f*(wprev + w0);
  float coef1 = 0.5f*(w0 + w1v);
  float dp = (lane<48) ? (w0*0.5f*(d0+d1) + w1v*0.5f*(d1+d2)) : 0.f;
  float wp = w0 + w1v;

  if (lane < 48){
    int src0 = (int)S[SL_SRC+s0], src1 = (int)S[SL_SRC+s1];
    Sf[SL_COEF+src0] = coef0;
    Sf[SL_COEF+src1] = coef1;
  }

  #pragma unroll
  for (int off=1; off<64; off<<=1){
    dp += __shfl_xor(dp, off);
    wp += __shfl_xor(wp, off);
  }

  // ---- color sum in MFMA C-layout, reduce over c16 ----
  float cc[8] = {0.f,0.f,0.f,0.f,0.f,0.f,0.f,0.f};
  #pragma unroll
  for (int n=0;n<3;n++){
    int pt = n*16 + c16;
    float cfC = Sf[SL_COEF + pt];
    float cfF = Sf[SL_COEF + 48 + pt];
    #pragma unroll
    for (int m2=0;m2<2;m2++){
      #pragma unroll
      for (int hw=0; hw<2; hw++){
        f16x2 hc = __builtin_bit_cast(f16x2, rgbC[(m2*3+n)*2+hw]);
        f16x2 hf = __builtin_bit_cast(f16x2, rgbF[(m2*3+n)*2+hw]);
        cc[m2*4+hw*2+0] += cfC*(float)hc[0] + cfF*(float)hf[0];
        cc[m2*4+hw*2+1] += cfC*(float)hc[1] + cfF*(float)hf[1];
      }
    }
  }
  #pragma unroll
  for (int off=1; off<16; off<<=1){
    #pragma unroll
    for (int i=0;i<8;i++) cc[i] += __shfl_xor(cc[i], off);
  }
  if (c16 == 0){
    #pragma unroll
    for (int m2=0;m2<2;m2++){
      f32x4 o4;
      #pragma unroll
      for (int r=0;r<4;r++) o4[r] = 2.0f*cc[m2*4+r] - 1.0f;
      *reinterpret_cast<f32x4*>(&out[(size_t)ray*32 + m2*16 + q*4]) = o4;
    }
  }
  if (lane == 0){
    out[OFF_DEPTH+ray] = dp;
    out[OFF_WSUM+ray]  = wp;
  }
}

extern "C" void kernel_launch(void* const* d_in, const int* in_sizes, int n_in,
                              void* d_out, int out_size, void* d_ws, size_t ws_size,
                              hipStream_t stream){
  const float* planes = (const float*)d_in[0];
  const float* orig   = (const float*)d_in[1];
  const float* dirs   = (const float*)d_in[2];
  const float* w1     = (const float*)d_in[3];
  const float* b1     = (const float*)d_in[4];
  const float* w2     = (const float*)d_in[5];
  const float* b2     = (const float*)d_in[6];
  float* out = (float*)d_out;
  char*  ws  = (char*)d_ws;

  f16*   pT    = (f16*)(ws + PT_B);
  f16*   w1A   = (f16*)(ws + W1A_B);
  float* b1F   = (float*)(ws + B1F_B);
  f16*   w2A   = (f16*)(ws + W2A_B);
  float* b2F   = (float*)(ws + B2F_B);

  k_transpose_prep<<<dim3(1537), dim3(256), 0, stream>>>(
      planes, w1, b1, w2, b2, pT, w1A, b1F, w2A, b2F);
  k_render<<<dim3(NRAY/4), dim3(256), 0, stream>>>(
      pT, orig, dirs, (const uint4*)w1A, (const f32x4*)b1F,
      (const uint4*)w2A, (const f32x4*)b2F, out);
}